// Round 6
// baseline (1060.507 us; speedup 1.0000x reference)
//
#include <hip/hip_runtime.h>

#define NB 16    // N*G
#define CD 64    // C == Cv
#define HD 2048  // H

typedef unsigned short u16;
typedef __attribute__((ext_vector_type(8))) short s16x8;  // 8 bf16 (4 VGPRs)
typedef __attribute__((ext_vector_type(4))) float f32x4;  // MFMA C/D

__device__ __forceinline__ u16 f2bf(float x){
    unsigned u = __float_as_uint(x);
    u += 0x7FFFu + ((u >> 16) & 1u);   // RNE
    return (u16)(u >> 16);
}
__device__ __forceinline__ float bf2f(u16 h){ return __uint_as_float(((unsigned)h) << 16); }
__device__ __forceinline__ void split2(float x, u16& h, u16& l){
    h = f2bf(x); l = f2bf(x - bf2f(h));   // x - hi is exact in fp32
}
union Frag { uint4 q; s16x8 s; };
__device__ __forceinline__ s16x8 ld8(const u16* p){ Frag f; f.q = *(const uint4*)p; return f.s; }
__device__ __forceinline__ f32x4 mfma16(s16x8 a, s16x8 b, f32x4 c){
    return __builtin_amdgcn_mfma_f32_16x16x32_bf16(a, b, c, 0, 0, 0);
}
// fp32-emulating triple MFMA: hi*hi + hi*lo + lo*hi
__device__ __forceinline__ f32x4 mm3(s16x8 ah, s16x8 al, s16x8 bh, s16x8 bl, f32x4 c){
    c = mfma16(ah, bh, c);
    c = mfma16(ah, bl, c);
    c = mfma16(al, bh, c);
    return c;
}
__device__ __forceinline__ f32x4 z4(){ f32x4 v = {0.f,0.f,0.f,0.f}; return v; }

// ---------------- prep kernels (unchanged) ----------------

__global__ void k_convert(const float* __restrict__ src, u16* __restrict__ dh,
                          u16* __restrict__ dl, int n4)
{
    int idx = blockIdx.x*256 + threadIdx.x;
    if (idx >= n4) return;
    float4 v = ((const float4*)src)[idx];
    ushort4 h, l;
    split2(v.x, h.x, l.x); split2(v.y, h.y, l.y);
    split2(v.z, h.z, l.z); split2(v.w, h.w, l.w);
    ((ushort4*)dh)[idx] = h;
    ((ushort4*)dl)[idx] = l;
}

__global__ void k_transpose(const float* __restrict__ src, u16* __restrict__ dh,
                            u16* __restrict__ dl)
{
    int bg = blockIdx.y, h0 = blockIdx.x*128, tid = threadIdx.x;
    __shared__ float ft[CD][132];
    #pragma unroll
    for (int k=0;k<8;k++){
        int flat = tid + 256*k;
        int c = flat >> 5, p = (flat & 31)*4;
        *(float4*)&ft[c][p] = *(const float4*)(src + ((size_t)bg*CD + c)*HD + h0 + p);
    }
    __syncthreads();
    int hl = tid >> 1, c0 = (tid & 1)*32;
    union { u16 u[32]; uint4 q[4]; } oh, ol;
    #pragma unroll
    for (int m=0;m<32;m++){
        float x = ft[c0+m][hl];
        u16 hh; split2(x, hh, ol.u[m]); oh.u[m] = hh;
    }
    size_t base = ((size_t)bg*HD + h0 + hl)*CD + c0;
    #pragma unroll
    for (int t=0;t<4;t++){
        *((uint4*)(dh + base) + t) = oh.q[t];
        *((uint4*)(dl + base) + t) = ol.q[t];
    }
}

__global__ void k_bias(const float* __restrict__ mu, const float* __restrict__ beta,
                       float* __restrict__ bias)
{
    int bg = blockIdx.y;
    int j  = blockIdx.x*256 + threadIdx.x;
    const float* m = mu + (size_t)bg*CD*HD + j;
    float s = 0.f;
    #pragma unroll
    for (int c=0;c<CD;c++){ float v = m[(size_t)c*HD]; s = fmaf(v, v, s); }
    bias[(size_t)bg*HD + j] = 0.5f * beta[0] * s;
}

// ---------------- k_rowsum: j-split halves; grid (64, NB) = 1024 blocks ----------------
__global__ __launch_bounds__(256,4) void k_rowsum(
    const u16* __restrict__ qTh, const u16* __restrict__ qTl,
    const u16* __restrict__ zTh, const u16* __restrict__ zTl,
    const float* __restrict__ bias, const float* __restrict__ alpha,
    float* __restrict__ r0, float* __restrict__ r1)
{
    const int bg = blockIdx.y, i0 = (blockIdx.x & 31)*64, jh = blockIdx.x >> 5;
    const int JB = jh*1024;
    float* rout = jh ? r1 : r0;
    const int tid = threadIdx.x, wave = tid>>6, lane = tid&63, ln = lane&15, quad = lane>>4;
    const int jw = wave*32;
    const float a = alpha[0];
    __shared__ float rpart[4][64];

    s16x8 Ah[4][2], Al[4][2];     // resident q^T frags: rows i0..i0+63
    #pragma unroll
    for (int mt=0;mt<4;mt++)
        #pragma unroll
        for (int ks=0;ks<2;ks++){
            size_t off = ((size_t)bg*HD + i0 + mt*16 + ln)*CD + ks*32 + quad*8;
            Ah[mt][ks] = ld8(qTh + off);
            Al[mt][ks] = ld8(qTl + off);
        }
    float racc[16];
    #pragma unroll
    for (int k=0;k<16;k++) racc[k] = 0.f;
    const float* bb = bias + (size_t)bg*HD + JB;

    s16x8 B0h[2][2], B0l[2][2], B1h[2][2], B1l[2][2];
    float bj0[2], bj1[2];

    // prologue: tile 0
    #pragma unroll
    for (int nt=0;nt<2;nt++){
        #pragma unroll
        for (int ks=0;ks<2;ks++){
            size_t off = ((size_t)bg*HD + JB + jw + nt*16 + ln)*CD + ks*32 + quad*8;
            B0h[nt][ks] = ld8(zTh + off);
            B0l[nt][ks] = ld8(zTl + off);
        }
        bj0[nt] = bb[jw + nt*16 + ln];
    }

    for (int j0=0;j0<1024;j0+=256){
        #pragma unroll
        for (int nt=0;nt<2;nt++){
            #pragma unroll
            for (int ks=0;ks<2;ks++){
                size_t off = ((size_t)bg*HD + JB + j0+128 + jw + nt*16 + ln)*CD + ks*32 + quad*8;
                B1h[nt][ks] = ld8(zTh + off);
                B1l[nt][ks] = ld8(zTl + off);
            }
            bj1[nt] = bb[j0+128 + jw + nt*16 + ln];
        }
        {
            f32x4 acc[4][2];
            #pragma unroll
            for (int mt=0;mt<4;mt++){ acc[mt][0]=z4(); acc[mt][1]=z4(); }
            #pragma unroll
            for (int ks=0;ks<2;ks++)
                #pragma unroll
                for (int mt=0;mt<4;mt++)
                    #pragma unroll
                    for (int nt=0;nt<2;nt++)
                        acc[mt][nt] = mm3(Ah[mt][ks], Al[mt][ks], B0h[nt][ks], B0l[nt][ks], acc[mt][nt]);
            #pragma unroll
            for (int mt=0;mt<4;mt++)
                #pragma unroll
                for (int nt=0;nt<2;nt++)
                    #pragma unroll
                    for (int rx=0;rx<4;rx++)
                        racc[mt*4+rx] += __expf(fmaf(a, acc[mt][nt][rx], bj0[nt]));
        }
        {
            int jn2 = (j0+256) & 1023;
            #pragma unroll
            for (int nt=0;nt<2;nt++){
                #pragma unroll
                for (int ks=0;ks<2;ks++){
                    size_t off = ((size_t)bg*HD + JB + jn2 + jw + nt*16 + ln)*CD + ks*32 + quad*8;
                    B0h[nt][ks] = ld8(zTh + off);
                    B0l[nt][ks] = ld8(zTl + off);
                }
                bj0[nt] = bb[jn2 + jw + nt*16 + ln];
            }
        }
        {
            f32x4 acc[4][2];
            #pragma unroll
            for (int mt=0;mt<4;mt++){ acc[mt][0]=z4(); acc[mt][1]=z4(); }
            #pragma unroll
            for (int ks=0;ks<2;ks++)
                #pragma unroll
                for (int mt=0;mt<4;mt++)
                    #pragma unroll
                    for (int nt=0;nt<2;nt++)
                        acc[mt][nt] = mm3(Ah[mt][ks], Al[mt][ks], B1h[nt][ks], B1l[nt][ks], acc[mt][nt]);
            #pragma unroll
            for (int mt=0;mt<4;mt++)
                #pragma unroll
                for (int nt=0;nt<2;nt++)
                    #pragma unroll
                    for (int rx=0;rx<4;rx++)
                        racc[mt*4+rx] += __expf(fmaf(a, acc[mt][nt][rx], bj1[nt]));
        }
    }
    #pragma unroll
    for (int k=0;k<16;k++){
        float v = racc[k];
        v += __shfl_xor(v,1); v += __shfl_xor(v,2);
        v += __shfl_xor(v,4); v += __shfl_xor(v,8);
        racc[k] = v;
    }
    if (ln == 0){
        #pragma unroll
        for (int mt=0;mt<4;mt++)
            #pragma unroll
            for (int rx=0;rx<4;rx++)
                rpart[wave][mt*16 + quad*4 + rx] = racc[mt*4+rx];
    }
    __syncthreads();
    if (tid < 64)
        rout[(size_t)bg*HD + i0 + tid] = rpart[0][tid]+rpart[1][tid]+rpart[2][tid]+rpart[3][tid];
}

// ---------------- k_update: i-split halves; grid (64, NB); partial num/den out ----------------
// Block: 64 j-cols, sweeps its i-half (8 steps of 128). Single-buffer LDS w-tile (33 KB)
// so 4 blocks/CU are resident; 2 barriers/step, stalls covered by 3 sibling blocks.
__global__ __launch_bounds__(256,4) void k_update(
    const u16* __restrict__ qTh, const u16* __restrict__ qTl,
    const u16* __restrict__ zTh, const u16* __restrict__ zTl,
    const u16* __restrict__ qNh, const u16* __restrict__ qNl,
    const float* __restrict__ bias, const float* __restrict__ alpha,
    const float* __restrict__ r0, const float* __restrict__ r1,
    float* __restrict__ numP, float* __restrict__ denP)
{
    const int bg = blockIdx.y, j0 = (blockIdx.x & 31)*64, ih = blockIdx.x >> 5;
    const int IB = ih << 10;
    const int tid = threadIdx.x, wave = tid>>6, lane = tid&63, ln = lane&15, quad = lane>>4;
    const int cm = (wave&1)*32, jn = (wave>>1)*32;
    const float a = alpha[0];
    __shared__ __align__(16) u16 wlh[64*128], wll[64*128];   // w^T tile [j][i], swizzled
    __shared__ float denl[4][64];

    s16x8 Bh[4][2], Bl[4][2];     // resident z^T frags: rows j0..j0+63 (read-only now)
    #pragma unroll
    for (int nt=0;nt<4;nt++)
        #pragma unroll
        for (int ks=0;ks<2;ks++){
            size_t off = ((size_t)bg*HD + j0 + nt*16 + ln)*CD + ks*32 + quad*8;
            Bh[nt][ks] = ld8(zTh + off);
            Bl[nt][ks] = ld8(zTl + off);
        }
    float bj[4];
    #pragma unroll
    for (int nt=0;nt<4;nt++) bj[nt] = bias[(size_t)bg*HD + j0 + nt*16 + ln];

    f32x4 acc2[2][2] = {{z4(),z4()},{z4(),z4()}};
    float den[4] = {0.f,0.f,0.f,0.f};

    for (int t=0; t<8; ++t){
        const int is = IB + t*128;
        // ---- phase-A operand loads (q^T) ----
        s16x8 Ah[2][2], Al[2][2];
        #pragma unroll
        for (int ks=0;ks<2;ks++)
            #pragma unroll
            for (int mt=0;mt<2;mt++){
                size_t off = ((size_t)bg*HD + is + wave*32 + mt*16 + ln)*CD + ks*32 + quad*8;
                Ah[mt][ks] = ld8(qTh + off);
                Al[mt][ks] = ld8(qTl + off);
            }
        // ---- first half of phase-B operand loads (qN, ks2=0,1) ----
        s16x8 A2h[4][2], A2l[4][2];
        #pragma unroll
        for (int ks2=0;ks2<2;ks2++)
            #pragma unroll
            for (int mtN=0;mtN<2;mtN++){
                size_t off = ((size_t)bg*CD + cm + mtN*16 + ln)*HD + is + ks2*32 + quad*8;
                A2h[ks2][mtN] = ld8(qNh + off);
                A2l[ks2][mtN] = ld8(qNl + off);
            }
        // ---- r loads (r = r0+r1 partials) ----
        float ri[8];
        #pragma unroll
        for (int mt=0;mt<2;mt++){
            size_t ro = (size_t)bg*HD + is + wave*32 + mt*16 + quad*4;
            float4 ra = *(const float4*)&r0[ro];
            float4 rb = *(const float4*)&r1[ro];
            ri[mt*4+0] = __builtin_amdgcn_rcpf(ra.x+rb.x);
            ri[mt*4+1] = __builtin_amdgcn_rcpf(ra.y+rb.y);
            ri[mt*4+2] = __builtin_amdgcn_rcpf(ra.z+rb.z);
            ri[mt*4+3] = __builtin_amdgcn_rcpf(ra.w+rb.w);
        }
        // ---- phase A MFMA ----
        f32x4 acc1[2][4];
        #pragma unroll
        for (int mt=0;mt<2;mt++)
            #pragma unroll
            for (int nt=0;nt<4;nt++) acc1[mt][nt] = z4();
        #pragma unroll
        for (int ks=0;ks<2;ks++)
            #pragma unroll
            for (int mt=0;mt<2;mt++)
                #pragma unroll
                for (int nt=0;nt<4;nt++)
                    acc1[mt][nt] = mm3(Ah[mt][ks], Al[mt][ks], Bh[nt][ks], Bl[nt][ks], acc1[mt][nt]);
        // ---- second half of phase-B loads (qN, ks2=2,3) ----
        #pragma unroll
        for (int ks2=2;ks2<4;ks2++)
            #pragma unroll
            for (int mtN=0;mtN<2;mtN++){
                size_t off = ((size_t)bg*CD + cm + mtN*16 + ln)*HD + is + ks2*32 + quad*8;
                A2h[ks2][mtN] = ld8(qNh + off);
                A2l[ks2][mtN] = ld8(qNl + off);
            }
        __syncthreads();   // previous step's phase-B LDS reads complete
        // ---- w compute + LDS write ----
        #pragma unroll
        for (int mt=0;mt<2;mt++)
            #pragma unroll
            for (int nt=0;nt<4;nt++){
                u16 hh[4], ll[4];
                #pragma unroll
                for (int rx=0;rx<4;rx++){
                    float w = __expf(fmaf(a, acc1[mt][nt][rx], bj[nt])) * ri[mt*4+rx];
                    den[nt] += w;
                    split2(w, hh[rx], ll[rx]);
                }
                int row = nt*16 + ln;                        // j-local
                int c4  = wave*32 + mt*16 + quad*4;          // i-local
                int off = (row<<7) + ((((c4>>3) ^ (row&15))<<3) | (c4&7));
                *(ushort4*)&wlh[off] = make_ushort4(hh[0],hh[1],hh[2],hh[3]);
                *(ushort4*)&wll[off] = make_ushort4(ll[0],ll[1],ll[2],ll[3]);
            }
        __syncthreads();
        // ---- phase B: LDS reads + MFMA ----
        #pragma unroll
        for (int ks2=0;ks2<4;ks2++){
            s16x8 B2h[2], B2l[2];
            #pragma unroll
            for (int nt2=0;nt2<2;nt2++){
                int jl = jn + nt2*16 + ln;
                int ob = (jl<<7) + (((ks2*4+quad) ^ (jl&15))<<3);
                B2h[nt2] = ld8(&wlh[ob]);
                B2l[nt2] = ld8(&wll[ob]);
            }
            #pragma unroll
            for (int mtN=0;mtN<2;mtN++)
                #pragma unroll
                for (int nt2=0;nt2<2;nt2++)
                    acc2[mtN][nt2] = mm3(A2h[ks2][mtN], A2l[ks2][mtN], B2h[nt2], B2l[nt2], acc2[mtN][nt2]);
        }
    }
    // den partial reduce + store
    #pragma unroll
    for (int nt=0;nt<4;nt++){
        float v = den[nt];
        v += __shfl_xor(v,16); v += __shfl_xor(v,32);
        if (quad == 0) denl[wave][nt*16 + ln] = v;
    }
    __syncthreads();
    if (tid < 64)
        denP[((size_t)ih*NB + bg)*HD + j0 + tid]
            = denl[0][tid]+denl[1][tid]+denl[2][tid]+denl[3][tid];
    // num partial store (f32)
    #pragma unroll
    for (int nt2=0;nt2<2;nt2++){
        int jl = jn + nt2*16 + ln;
        #pragma unroll
        for (int mtN=0;mtN<2;mtN++){
            size_t off = (size_t)ih*NB*HD*CD
                       + ((size_t)bg*HD + j0 + jl)*CD + cm + mtN*16 + quad*4;
            *(float4*)&numP[off] = *(float4*)&acc2[mtN][nt2];
        }
    }
}

// zeta = num/den, split2, write z^T (layout [bg][j][c] == flat num layout)
__global__ void k_zcomb(const float* __restrict__ numP, const float* __restrict__ denP,
                        u16* __restrict__ zTh, u16* __restrict__ zTl)
{
    size_t f = ((size_t)blockIdx.x*256 + threadIdx.x) * 4;
    size_t jg = f >> 6;                       // bg*HD + j
    float4 n0 = *(const float4*)&numP[f];
    float4 n1 = *(const float4*)&numP[(size_t)NB*HD*CD + f];
    float di = __builtin_amdgcn_rcpf(denP[jg] + denP[(size_t)NB*HD + jg]);
    ushort4 h, l;
    split2((n0.x+n1.x)*di, h.x, l.x);
    split2((n0.y+n1.y)*di, h.y, l.y);
    split2((n0.z+n1.z)*di, h.z, l.z);
    split2((n0.w+n1.w)*di, h.w, l.w);
    *(ushort4*)&zTh[f] = h;
    *(ushort4*)&zTl[f] = l;
}

// ---------------- k_final: j-split halves; grid (64, NB); partial num/r out ----------------
__global__ __launch_bounds__(256,4) void k_final(
    const u16* __restrict__ qTh, const u16* __restrict__ qTl,
    const u16* __restrict__ zTh, const u16* __restrict__ zTl,
    const u16* __restrict__ muh, const u16* __restrict__ mul_,
    const float* __restrict__ bias, const float* __restrict__ alpha,
    float* __restrict__ numP, float* __restrict__ rP)
{
    const int bg = blockIdx.y, i0 = (blockIdx.x & 31)*64, jh = blockIdx.x >> 5;
    const int JB = jh << 10;
    const int tid = threadIdx.x, wave = tid>>6, lane = tid&63, ln = lane&15, quad = lane>>4;
    const int cm = (wave&1)*32, in_ = (wave>>1)*32;
    const float a = alpha[0];
    __shared__ __align__(16) u16 elh[64*128], ell[64*128];   // e^T tile [i][j], swizzled
    __shared__ float rl2[4][64];

    s16x8 Bh[4][2], Bl[4][2];     // resident q^T frags: rows i0..i0+63 (n operand)
    #pragma unroll
    for (int nt=0;nt<4;nt++)
        #pragma unroll
        for (int ks=0;ks<2;ks++){
            size_t off = ((size_t)bg*HD + i0 + nt*16 + ln)*CD + ks*32 + quad*8;
            Bh[nt][ks] = ld8(qTh + off);
            Bl[nt][ks] = ld8(qTl + off);
        }
    f32x4 acc2[2][2] = {{z4(),z4()},{z4(),z4()}};
    float racc[4] = {0.f,0.f,0.f,0.f};

    for (int t=0; t<8; ++t){
        const int js = JB + t*128;
        // ---- phase-A operand loads (z^T) ----
        s16x8 Ah[2][2], Al[2][2];
        #pragma unroll
        for (int ks=0;ks<2;ks++)
            #pragma unroll
            for (int mt=0;mt<2;mt++){
                size_t off = ((size_t)bg*HD + js + wave*32 + mt*16 + ln)*CD + ks*32 + quad*8;
                Ah[mt][ks] = ld8(zTh + off);
                Al[mt][ks] = ld8(zTl + off);
            }
        // ---- first half of phase-B operand loads (mu, ks2=0,1) ----
        s16x8 A2h[4][2], A2l[4][2];
        #pragma unroll
        for (int ks2=0;ks2<2;ks2++)
            #pragma unroll
            for (int mtN=0;mtN<2;mtN++){
                size_t off = ((size_t)bg*CD + cm + mtN*16 + ln)*HD + js + ks2*32 + quad*8;
                A2h[ks2][mtN] = ld8(muh + off);
                A2l[ks2][mtN] = ld8(mul_ + off);
            }
        // ---- bias loads (vectorized) ----
        float bj8[8];
        #pragma unroll
        for (int mt=0;mt<2;mt++){
            float4 bv = *(const float4*)&bias[(size_t)bg*HD + js + wave*32 + mt*16 + quad*4];
            bj8[mt*4+0]=bv.x; bj8[mt*4+1]=bv.y; bj8[mt*4+2]=bv.z; bj8[mt*4+3]=bv.w;
        }
        // ---- phase A MFMA: S'[j][i] (m = j, n = i) ----
        f32x4 acc1[2][4];
        #pragma unroll
        for (int mt=0;mt<2;mt++)
            #pragma unroll
            for (int nt=0;nt<4;nt++) acc1[mt][nt] = z4();
        #pragma unroll
        for (int ks=0;ks<2;ks++)
            #pragma unroll
            for (int mt=0;mt<2;mt++)
                #pragma unroll
                for (int nt=0;nt<4;nt++)
                    acc1[mt][nt] = mm3(Ah[mt][ks], Al[mt][ks], Bh[nt][ks], Bl[nt][ks], acc1[mt][nt]);
        // ---- second half of phase-B loads (mu, ks2=2,3) ----
        #pragma unroll
        for (int ks2=2;ks2<4;ks2++)
            #pragma unroll
            for (int mtN=0;mtN<2;mtN++){
                size_t off = ((size_t)bg*CD + cm + mtN*16 + ln)*HD + js + ks2*32 + quad*8;
                A2h[ks2][mtN] = ld8(muh + off);
                A2l[ks2][mtN] = ld8(mul_ + off);
            }
        __syncthreads();   // previous step's phase-B LDS reads complete
        // ---- e compute + LDS write ----
        #pragma unroll
        for (int mt=0;mt<2;mt++)
            #pragma unroll
            for (int nt=0;nt<4;nt++){
                u16 hh[4], ll[4];
                #pragma unroll
                for (int rx=0;rx<4;rx++){
                    float e = __expf(fmaf(a, acc1[mt][nt][rx], bj8[mt*4+rx]));
                    racc[nt] += e;
                    split2(e, hh[rx], ll[rx]);
                }
                int row = nt*16 + ln;                        // i-local
                int c4  = wave*32 + mt*16 + quad*4;          // j-local
                int off = (row<<7) + ((((c4>>3) ^ (row&15))<<3) | (c4&7));
                *(ushort4*)&elh[off] = make_ushort4(hh[0],hh[1],hh[2],hh[3]);
                *(ushort4*)&ell[off] = make_ushort4(ll[0],ll[1],ll[2],ll[3]);
            }
        __syncthreads();
        // ---- phase B: acc2[c][i] += mu * e^T ----
        #pragma unroll
        for (int ks2=0;ks2<4;ks2++){
            s16x8 B2h[2], B2l[2];
            #pragma unroll
            for (int nt2=0;nt2<2;nt2++){
                int il = in_ + nt2*16 + ln;
                int ob = (il<<7) + (((ks2*4+quad) ^ (il&15))<<3);
                B2h[nt2] = ld8(&elh[ob]);
                B2l[nt2] = ld8(&ell[ob]);
            }
            #pragma unroll
            for (int mtN=0;mtN<2;mtN++)
                #pragma unroll
                for (int nt2=0;nt2<2;nt2++)
                    acc2[mtN][nt2] = mm3(A2h[ks2][mtN], A2l[ks2][mtN], B2h[nt2], B2l[nt2], acc2[mtN][nt2]);
        }
    }
    // r partial reduce + store
    #pragma unroll
    for (int nt=0;nt<4;nt++){
        float v = racc[nt];
        v += __shfl_xor(v,16); v += __shfl_xor(v,32);
        if (quad == 0) rl2[wave][nt*16 + ln] = v;
    }
    __syncthreads();
    if (tid < 64)
        rP[((size_t)jh*NB + bg)*HD + i0 + tid]
            = rl2[0][tid]+rl2[1][tid]+rl2[2][tid]+rl2[3][tid];
    // num partial store (f32, out layout)
    #pragma unroll
    for (int nt2=0;nt2<2;nt2++){
        int il = in_ + nt2*16 + ln;
        #pragma unroll
        for (int mtN=0;mtN<2;mtN++)
            #pragma unroll
            for (int rx=0;rx<4;rx++)
                numP[(size_t)jh*NB*HD*CD
                     + ((size_t)bg*CD + cm + mtN*16 + quad*4 + rx)*HD + i0 + il]
                    = acc2[mtN][nt2][rx];
    }
}

// out = num/r  (layout [bg][c][i] == flat num layout)
__global__ void k_ocomb(const float* __restrict__ numP, const float* __restrict__ rP,
                        float* __restrict__ out)
{
    size_t f = ((size_t)blockIdx.x*256 + threadIdx.x) * 4;
    size_t bg = f >> 17;                      // CD*HD = 1<<17
    size_t ibase = (bg << 11) + (f & (HD-1));
    float4 n0 = *(const float4*)&numP[f];
    float4 n1 = *(const float4*)&numP[(size_t)NB*HD*CD + f];
    float4 ra = *(const float4*)&rP[ibase];
    float4 rb = *(const float4*)&rP[(size_t)NB*HD + ibase];
    float4 o;
    o.x = (n0.x+n1.x)*__builtin_amdgcn_rcpf(ra.x+rb.x);
    o.y = (n0.y+n1.y)*__builtin_amdgcn_rcpf(ra.y+rb.y);
    o.z = (n0.z+n1.z)*__builtin_amdgcn_rcpf(ra.z+rb.z);
    o.w = (n0.w+n1.w)*__builtin_amdgcn_rcpf(ra.w+rb.w);
    *(float4*)&out[f] = o;
}

extern "C" void kernel_launch(void* const* d_in, const int* in_sizes, int n_in,
                              void* d_out, int out_size, void* d_ws, size_t ws_size,
                              hipStream_t stream)
{
    (void)in_sizes; (void)n_in; (void)out_size; (void)ws_size;
    const float* q     = (const float*)d_in[0];
    const float* zeta  = (const float*)d_in[1];
    const float* alpha = (const float*)d_in[2];
    const float* mu    = (const float*)d_in[3];
    const float* beta  = (const float*)d_in[4];
    float* out = (float*)d_out;

    const size_t SZ = (size_t)NB*HD*CD;   // elements per tensor (2M)
    u16* qTh = (u16*)d_ws;
    u16* qTl = qTh + 1*SZ;
    u16* zTh = qTh + 2*SZ;
    u16* zTl = qTh + 3*SZ;
    u16* qNh = qTh + 4*SZ;
    u16* qNl = qTh + 5*SZ;
    u16* muh = qTh + 6*SZ;
    u16* mul_= qTh + 7*SZ;
    float* bias = (float*)(qTh + 8*SZ);
    float* r0   = bias + (size_t)NB*HD;
    float* r1   = r0   + (size_t)NB*HD;
    float* denP = r1   + (size_t)NB*HD;          // [2][NB*HD]
    float* rP   = denP + (size_t)2*NB*HD;        // [2][NB*HD]
    float* numP = rP   + (size_t)2*NB*HD;        // [2][SZ] f32 (reused update->final)

    dim3 blk(256,1,1);
    int n4 = (int)(SZ/4);
    k_convert  <<<dim3(n4/256), blk, 0, stream>>>(q,  qNh, qNl, n4);
    k_convert  <<<dim3(n4/256), blk, 0, stream>>>(mu, muh, mul_, n4);
    k_transpose<<<dim3(HD/128, NB), blk, 0, stream>>>(q,    qTh, qTl);
    k_transpose<<<dim3(HD/128, NB), blk, 0, stream>>>(zeta, zTh, zTl);
    k_bias     <<<dim3(HD/256, NB), blk, 0, stream>>>(mu, beta, bias);

    k_rowsum<<<dim3(64, NB), blk, 0, stream>>>(qTh,qTl,zTh,zTl,bias,alpha,r0,r1);
    k_update<<<dim3(64, NB), blk, 0, stream>>>(qTh,qTl,zTh,zTl,qNh,qNl,bias,alpha,r0,r1,numP,denP);
    k_zcomb <<<dim3((int)(SZ/4/256)), blk, 0, stream>>>(numP,denP,zTh,zTl);
    k_rowsum<<<dim3(64, NB), blk, 0, stream>>>(qTh,qTl,zTh,zTl,bias,alpha,r0,r1);
    k_update<<<dim3(64, NB), blk, 0, stream>>>(qTh,qTl,zTh,zTl,qNh,qNl,bias,alpha,r0,r1,numP,denP);
    k_zcomb <<<dim3((int)(SZ/4/256)), blk, 0, stream>>>(numP,denP,zTh,zTl);
    k_final <<<dim3(64, NB), blk, 0, stream>>>(qTh,qTl,zTh,zTl,muh,mul_,bias,alpha,numP,rP);
    k_ocomb <<<dim3((int)(SZ/4/256)), blk, 0, stream>>>(numP,rP,out);
}

// Round 7
// 648.022 us; speedup vs baseline: 1.6365x; 1.6365x over previous
//
#include <hip/hip_runtime.h>

#define NB 16    // N*G
#define CD 64    // C == Cv
#define HD 2048  // H

typedef unsigned short u16;
typedef __attribute__((ext_vector_type(8))) short s16x8;  // 8 bf16 (4 VGPRs)
typedef __attribute__((ext_vector_type(4))) float f32x4;  // MFMA C/D

__device__ __forceinline__ u16 f2bf(float x){
    unsigned u = __float_as_uint(x);
    u += 0x7FFFu + ((u >> 16) & 1u);   // RNE
    return (u16)(u >> 16);
}
__device__ __forceinline__ float bf2f(u16 h){ return __uint_as_float(((unsigned)h) << 16); }
__device__ __forceinline__ void split2(float x, u16& h, u16& l){
    h = f2bf(x); l = f2bf(x - bf2f(h));   // x - hi is exact in fp32
}
union Frag { uint4 q; s16x8 s; };
__device__ __forceinline__ s16x8 ld8(const u16* p){ Frag f; f.q = *(const uint4*)p; return f.s; }
__device__ __forceinline__ f32x4 mfma16(s16x8 a, s16x8 b, f32x4 c){
    return __builtin_amdgcn_mfma_f32_16x16x32_bf16(a, b, c, 0, 0, 0);
}
// fp32-emulating triple MFMA: hi*hi + hi*lo + lo*hi
__device__ __forceinline__ f32x4 mm3(s16x8 ah, s16x8 al, s16x8 bh, s16x8 bl, f32x4 c){
    c = mfma16(ah, bh, c);
    c = mfma16(ah, bl, c);
    c = mfma16(al, bh, c);
    return c;
}
__device__ __forceinline__ f32x4 z4(){ f32x4 v = {0.f,0.f,0.f,0.f}; return v; }

// ---------------- prep kernels (unchanged) ----------------

__global__ void k_convert(const float* __restrict__ src, u16* __restrict__ dh,
                          u16* __restrict__ dl, int n4)
{
    int idx = blockIdx.x*256 + threadIdx.x;
    if (idx >= n4) return;
    float4 v = ((const float4*)src)[idx];
    ushort4 h, l;
    split2(v.x, h.x, l.x); split2(v.y, h.y, l.y);
    split2(v.z, h.z, l.z); split2(v.w, h.w, l.w);
    ((ushort4*)dh)[idx] = h;
    ((ushort4*)dl)[idx] = l;
}

__global__ void k_transpose(const float* __restrict__ src, u16* __restrict__ dh,
                            u16* __restrict__ dl)
{
    int bg = blockIdx.y, h0 = blockIdx.x*128, tid = threadIdx.x;
    __shared__ float ft[CD][132];
    #pragma unroll
    for (int k=0;k<8;k++){
        int flat = tid + 256*k;
        int c = flat >> 5, p = (flat & 31)*4;
        *(float4*)&ft[c][p] = *(const float4*)(src + ((size_t)bg*CD + c)*HD + h0 + p);
    }
    __syncthreads();
    int hl = tid >> 1, c0 = (tid & 1)*32;
    union { u16 u[32]; uint4 q[4]; } oh, ol;
    #pragma unroll
    for (int m=0;m<32;m++){
        float x = ft[c0+m][hl];
        u16 hh; split2(x, hh, ol.u[m]); oh.u[m] = hh;
    }
    size_t base = ((size_t)bg*HD + h0 + hl)*CD + c0;
    #pragma unroll
    for (int t=0;t<4;t++){
        *((uint4*)(dh + base) + t) = oh.q[t];
        *((uint4*)(dl + base) + t) = ol.q[t];
    }
}

__global__ void k_bias(const float* __restrict__ mu, const float* __restrict__ beta,
                       float* __restrict__ bias)
{
    int bg = blockIdx.y;
    int j  = blockIdx.x*256 + threadIdx.x;
    const float* m = mu + (size_t)bg*CD*HD + j;
    float s = 0.f;
    #pragma unroll
    for (int c=0;c<CD;c++){ float v = m[(size_t)c*HD]; s = fmaf(v, v, s); }
    bias[(size_t)bg*HD + j] = 0.5f * beta[0] * s;
}

// ---------------- main MFMA kernels ----------------
// 32-wide resident tiles -> grid 1024 blocks -> 4 blocks/CU packed by the HW from
// actual resources (VGPR ~128, LDS ~33 KB). launch_bounds(256,2) is the only config
// the allocator handles without spilling (r3/r5 evidence); occupancy comes from the
// grid, NOT from the allocator.

// r[i] = sum_j exp(a*S+bias_j). Block: 32 i-rows resident; waves split j; register
// double-buffered B tile. Grid (HD/32, NB).
__global__ __launch_bounds__(256,2) void k_rowsum(
    const u16* __restrict__ qTh, const u16* __restrict__ qTl,
    const u16* __restrict__ zTh, const u16* __restrict__ zTl,
    const float* __restrict__ bias, const float* __restrict__ alpha,
    float* __restrict__ r)
{
    const int bg = blockIdx.y, i0 = blockIdx.x*32;
    const int tid = threadIdx.x, wave = tid>>6, lane = tid&63, ln = lane&15, quad = lane>>4;
    const int jw = wave*32;
    const float a = alpha[0];
    __shared__ float rpart[4][32];

    s16x8 Ah[2][2], Al[2][2];     // resident q^T frags: rows i0..i0+31
    #pragma unroll
    for (int mt=0;mt<2;mt++)
        #pragma unroll
        for (int ks=0;ks<2;ks++){
            size_t off = ((size_t)bg*HD + i0 + mt*16 + ln)*CD + ks*32 + quad*8;
            Ah[mt][ks] = ld8(qTh + off);
            Al[mt][ks] = ld8(qTl + off);
        }
    float racc[8];
    #pragma unroll
    for (int k=0;k<8;k++) racc[k] = 0.f;
    const float* bb = bias + (size_t)bg*HD;

    s16x8 B0h[2][2], B0l[2][2], B1h[2][2], B1l[2][2];
    float bj0[2], bj1[2];

    // prologue: tile 0
    #pragma unroll
    for (int nt=0;nt<2;nt++){
        #pragma unroll
        for (int ks=0;ks<2;ks++){
            size_t off = ((size_t)bg*HD + jw + nt*16 + ln)*CD + ks*32 + quad*8;
            B0h[nt][ks] = ld8(zTh + off);
            B0l[nt][ks] = ld8(zTl + off);
        }
        bj0[nt] = bb[jw + nt*16 + ln];
    }

    for (int j0=0;j0<HD;j0+=256){
        // issue loads for tile j0+128 into B1
        #pragma unroll
        for (int nt=0;nt<2;nt++){
            #pragma unroll
            for (int ks=0;ks<2;ks++){
                size_t off = ((size_t)bg*HD + j0+128 + jw + nt*16 + ln)*CD + ks*32 + quad*8;
                B1h[nt][ks] = ld8(zTh + off);
                B1l[nt][ks] = ld8(zTl + off);
            }
            bj1[nt] = bb[j0+128 + jw + nt*16 + ln];
        }
        // compute tile j0 with B0
        {
            f32x4 acc[2][2];
            #pragma unroll
            for (int mt=0;mt<2;mt++){ acc[mt][0]=z4(); acc[mt][1]=z4(); }
            #pragma unroll
            for (int ks=0;ks<2;ks++)
                #pragma unroll
                for (int mt=0;mt<2;mt++)
                    #pragma unroll
                    for (int nt=0;nt<2;nt++)
                        acc[mt][nt] = mm3(Ah[mt][ks], Al[mt][ks], B0h[nt][ks], B0l[nt][ks], acc[mt][nt]);
            #pragma unroll
            for (int mt=0;mt<2;mt++)
                #pragma unroll
                for (int nt=0;nt<2;nt++)
                    #pragma unroll
                    for (int rx=0;rx<4;rx++)
                        racc[mt*4+rx] += __expf(fmaf(a, acc[mt][nt][rx], bj0[nt]));
        }
        // issue loads for tile (j0+256)&(HD-1) into B0 (wraps on last iter; unused)
        {
            int jn2 = (j0+256) & (HD-1);
            #pragma unroll
            for (int nt=0;nt<2;nt++){
                #pragma unroll
                for (int ks=0;ks<2;ks++){
                    size_t off = ((size_t)bg*HD + jn2 + jw + nt*16 + ln)*CD + ks*32 + quad*8;
                    B0h[nt][ks] = ld8(zTh + off);
                    B0l[nt][ks] = ld8(zTl + off);
                }
                bj0[nt] = bb[jn2 + jw + nt*16 + ln];
            }
        }
        // compute tile j0+128 with B1
        {
            f32x4 acc[2][2];
            #pragma unroll
            for (int mt=0;mt<2;mt++){ acc[mt][0]=z4(); acc[mt][1]=z4(); }
            #pragma unroll
            for (int ks=0;ks<2;ks++)
                #pragma unroll
                for (int mt=0;mt<2;mt++)
                    #pragma unroll
                    for (int nt=0;nt<2;nt++)
                        acc[mt][nt] = mm3(Ah[mt][ks], Al[mt][ks], B1h[nt][ks], B1l[nt][ks], acc[mt][nt]);
            #pragma unroll
            for (int mt=0;mt<2;mt++)
                #pragma unroll
                for (int nt=0;nt<2;nt++)
                    #pragma unroll
                    for (int rx=0;rx<4;rx++)
                        racc[mt*4+rx] += __expf(fmaf(a, acc[mt][nt][rx], bj1[nt]));
        }
    }
    #pragma unroll
    for (int k=0;k<8;k++){
        float v = racc[k];
        v += __shfl_xor(v,1); v += __shfl_xor(v,2);
        v += __shfl_xor(v,4); v += __shfl_xor(v,8);
        racc[k] = v;
    }
    if (ln == 0){
        #pragma unroll
        for (int mt=0;mt<2;mt++)
            #pragma unroll
            for (int rx=0;rx<4;rx++)
                rpart[wave][mt*16 + quad*4 + rx] = racc[mt*4+rx];
    }
    __syncthreads();
    if (tid < 32)
        r[(size_t)bg*HD + i0 + tid] = rpart[0][tid]+rpart[1][tid]+rpart[2][tid]+rpart[3][tid];
}

// zeta update. Block: 32 j-cols resident, sweeps full i (16 steps of 128).
// Phase A per wave: [32 i][32 j]; phase B per wave: [16 c][32 j]. LDS double-buffered,
// one barrier per step. Grid (HD/32, NB).
__global__ __launch_bounds__(256,2) void k_update(
    const u16* __restrict__ qTh, const u16* __restrict__ qTl,
    u16* zTh, u16* zTl,                               // read then overwritten (own rows only)
    const u16* __restrict__ qNh, const u16* __restrict__ qNl,
    const float* __restrict__ bias, const float* __restrict__ alpha,
    const float* __restrict__ r)
{
    const int bg = blockIdx.y, j0 = blockIdx.x*32;
    const int tid = threadIdx.x, wave = tid>>6, lane = tid&63, ln = lane&15, quad = lane>>4;
    const int iw = wave*32;       // phase A i-chunk within the 128-step
    const int cm = wave*16;       // phase B c-chunk
    const float a = alpha[0];
    __shared__ __align__(16) u16 wlh[2][32*128], wll[2][32*128];  // w^T tile [j][i], swizzled
    __shared__ float denl[4][32];

    s16x8 Bh[2][2], Bl[2][2];     // resident z^T frags: rows j0..j0+31 (read before any write)
    #pragma unroll
    for (int nt=0;nt<2;nt++)
        #pragma unroll
        for (int ks=0;ks<2;ks++){
            size_t off = ((size_t)bg*HD + j0 + nt*16 + ln)*CD + ks*32 + quad*8;
            Bh[nt][ks] = ld8(zTh + off);
            Bl[nt][ks] = ld8(zTl + off);
        }
    float bj[2];
    #pragma unroll
    for (int nt=0;nt<2;nt++) bj[nt] = bias[(size_t)bg*HD + j0 + nt*16 + ln];

    f32x4 acc2[2] = {z4(), z4()};
    float den[2] = {0.f, 0.f};
    int buf = 0;

    for (int is=0; is<HD; is+=128, buf^=1){
        // ---- phase-A operand loads (q^T rows is+iw..+31) ----
        s16x8 Ah[2][2], Al[2][2];
        #pragma unroll
        for (int ks=0;ks<2;ks++)
            #pragma unroll
            for (int mt=0;mt<2;mt++){
                size_t off = ((size_t)bg*HD + is + iw + mt*16 + ln)*CD + ks*32 + quad*8;
                Ah[mt][ks] = ld8(qTh + off);
                Al[mt][ks] = ld8(qTl + off);
            }
        // ---- first half of phase-B operand loads (qN rows cm..cm+15, ks2=0,1) ----
        s16x8 A2h[4], A2l[4];
        #pragma unroll
        for (int ks2=0;ks2<2;ks2++){
            size_t off = ((size_t)bg*CD + cm + ln)*HD + is + ks2*32 + quad*8;
            A2h[ks2] = ld8(qNh + off);
            A2l[ks2] = ld8(qNl + off);
        }
        // ---- r loads (vectorized) ----
        float ri[8];
        #pragma unroll
        for (int mt=0;mt<2;mt++){
            float4 rv = *(const float4*)&r[(size_t)bg*HD + is + iw + mt*16 + quad*4];
            ri[mt*4+0] = __builtin_amdgcn_rcpf(rv.x);
            ri[mt*4+1] = __builtin_amdgcn_rcpf(rv.y);
            ri[mt*4+2] = __builtin_amdgcn_rcpf(rv.z);
            ri[mt*4+3] = __builtin_amdgcn_rcpf(rv.w);
        }
        // ---- phase A MFMA ----
        f32x4 acc1[2][2];
        #pragma unroll
        for (int mt=0;mt<2;mt++){ acc1[mt][0]=z4(); acc1[mt][1]=z4(); }
        #pragma unroll
        for (int ks=0;ks<2;ks++)
            #pragma unroll
            for (int mt=0;mt<2;mt++)
                #pragma unroll
                for (int nt=0;nt<2;nt++)
                    acc1[mt][nt] = mm3(Ah[mt][ks], Al[mt][ks], Bh[nt][ks], Bl[nt][ks], acc1[mt][nt]);
        // ---- second half of phase-B loads (ks2=2,3) ----
        #pragma unroll
        for (int ks2=2;ks2<4;ks2++){
            size_t off = ((size_t)bg*CD + cm + ln)*HD + is + ks2*32 + quad*8;
            A2h[ks2] = ld8(qNh + off);
            A2l[ks2] = ld8(qNl + off);
        }
        // ---- w compute + LDS write (buffer `buf`) ----
        #pragma unroll
        for (int mt=0;mt<2;mt++)
            #pragma unroll
            for (int nt=0;nt<2;nt++){
                u16 hh[4], ll[4];
                #pragma unroll
                for (int rx=0;rx<4;rx++){
                    float w = __expf(fmaf(a, acc1[mt][nt][rx], bj[nt])) * ri[mt*4+rx];
                    den[nt] += w;
                    split2(w, hh[rx], ll[rx]);
                }
                int row = nt*16 + ln;                        // j-local (0..31)
                int c4  = iw + mt*16 + quad*4;               // i-local (0..127)
                int off = (row<<7) + ((((c4>>3) ^ (row&15))<<3) | (c4&7));
                *(ushort4*)&wlh[buf][off] = make_ushort4(hh[0],hh[1],hh[2],hh[3]);
                *(ushort4*)&wll[buf][off] = make_ushort4(ll[0],ll[1],ll[2],ll[3]);
            }
        __syncthreads();
        // ---- phase B: LDS reads + MFMA (global operands already in regs) ----
        #pragma unroll
        for (int ks2=0;ks2<4;ks2++){
            s16x8 B2h[2], B2l[2];
            #pragma unroll
            for (int nt2=0;nt2<2;nt2++){
                int jl = nt2*16 + ln;
                int ob = (jl<<7) + (((ks2*4+quad) ^ (jl&15))<<3);
                B2h[nt2] = ld8(&wlh[buf][ob]);
                B2l[nt2] = ld8(&wll[buf][ob]);
            }
            #pragma unroll
            for (int nt2=0;nt2<2;nt2++)
                acc2[nt2] = mm3(A2h[ks2], A2l[ks2], B2h[nt2], B2l[nt2], acc2[nt2]);
        }
    }
    // denominator reduce: quads via shfl, waves via LDS
    #pragma unroll
    for (int nt=0;nt<2;nt++){
        float v = den[nt];
        v += __shfl_xor(v,16); v += __shfl_xor(v,32);
        if (quad == 0) denl[wave][nt*16 + ln] = v;
    }
    __syncthreads();
    #pragma unroll
    for (int nt2=0;nt2<2;nt2++){
        int jl = nt2*16 + ln;
        float dinv = __builtin_amdgcn_rcpf(denl[0][jl]+denl[1][jl]+denl[2][jl]+denl[3][jl]);
        u16 hh[4], ll[4];
        #pragma unroll
        for (int rx=0;rx<4;rx++){
            float v = acc2[nt2][rx] * dinv;
            split2(v, hh[rx], ll[rx]);
        }
        size_t off = ((size_t)bg*HD + j0 + jl)*CD + cm + quad*4;
        *(ushort4*)(zTh + off) = make_ushort4(hh[0],hh[1],hh[2],hh[3]);
        *(ushort4*)(zTl + off) = make_ushort4(ll[0],ll[1],ll[2],ll[3]);
    }
}

// final: out[c][i] = (sum_j e_ij mu_cj) / (sum_j e_ij). Block: 32 i-cols resident,
// sweeps full j. Grid (HD/32, NB).
__global__ __launch_bounds__(256,2) void k_final(
    const u16* __restrict__ qTh, const u16* __restrict__ qTl,
    const u16* __restrict__ zTh, const u16* __restrict__ zTl,
    const u16* __restrict__ muh, const u16* __restrict__ mul_,
    const float* __restrict__ bias, const float* __restrict__ alpha,
    float* __restrict__ out)
{
    const int bg = blockIdx.y, i0 = blockIdx.x*32;
    const int tid = threadIdx.x, wave = tid>>6, lane = tid&63, ln = lane&15, quad = lane>>4;
    const int jm = wave*32;       // phase A j-chunk within the 128-step
    const int cm = wave*16;       // phase B c-chunk
    const float a = alpha[0];
    __shared__ __align__(16) u16 elh[2][32*128], ell[2][32*128];  // e^T tile [i][j], swizzled
    __shared__ float rl2[4][32];

    s16x8 Bh[2][2], Bl[2][2];     // resident q^T frags: rows i0..i0+31 (n operand)
    #pragma unroll
    for (int nt=0;nt<2;nt++)
        #pragma unroll
        for (int ks=0;ks<2;ks++){
            size_t off = ((size_t)bg*HD + i0 + nt*16 + ln)*CD + ks*32 + quad*8;
            Bh[nt][ks] = ld8(qTh + off);
            Bl[nt][ks] = ld8(qTl + off);
        }
    f32x4 acc2[2] = {z4(), z4()};
    float racc[2] = {0.f, 0.f};
    int buf = 0;

    for (int js=0; js<HD; js+=128, buf^=1){
        // ---- phase-A operand loads (z^T rows js+jm..+31) ----
        s16x8 Ah[2][2], Al[2][2];
        #pragma unroll
        for (int ks=0;ks<2;ks++)
            #pragma unroll
            for (int mt=0;mt<2;mt++){
                size_t off = ((size_t)bg*HD + js + jm + mt*16 + ln)*CD + ks*32 + quad*8;
                Ah[mt][ks] = ld8(zTh + off);
                Al[mt][ks] = ld8(zTl + off);
            }
        // ---- first half of phase-B operand loads (mu rows cm..cm+15, ks2=0,1) ----
        s16x8 A2h[4], A2l[4];
        #pragma unroll
        for (int ks2=0;ks2<2;ks2++){
            size_t off = ((size_t)bg*CD + cm + ln)*HD + js + ks2*32 + quad*8;
            A2h[ks2] = ld8(muh + off);
            A2l[ks2] = ld8(mul_ + off);
        }
        // ---- bias loads (vectorized) ----
        float bj8[8];
        #pragma unroll
        for (int mt=0;mt<2;mt++){
            float4 bv = *(const float4*)&bias[(size_t)bg*HD + js + jm + mt*16 + quad*4];
            bj8[mt*4+0]=bv.x; bj8[mt*4+1]=bv.y; bj8[mt*4+2]=bv.z; bj8[mt*4+3]=bv.w;
        }
        // ---- phase A MFMA: S'[j][i] (m = j, n = i) ----
        f32x4 acc1[2][2];
        #pragma unroll
        for (int mt=0;mt<2;mt++){ acc1[mt][0]=z4(); acc1[mt][1]=z4(); }
        #pragma unroll
        for (int ks=0;ks<2;ks++)
            #pragma unroll
            for (int mt=0;mt<2;mt++)
                #pragma unroll
                for (int nt=0;nt<2;nt++)
                    acc1[mt][nt] = mm3(Ah[mt][ks], Al[mt][ks], Bh[nt][ks], Bl[nt][ks], acc1[mt][nt]);
        // ---- second half of phase-B loads (ks2=2,3) ----
        #pragma unroll
        for (int ks2=2;ks2<4;ks2++){
            size_t off = ((size_t)bg*CD + cm + ln)*HD + js + ks2*32 + quad*8;
            A2h[ks2] = ld8(muh + off);
            A2l[ks2] = ld8(mul_ + off);
        }
        // ---- e compute + LDS write (buffer `buf`) ----
        #pragma unroll
        for (int mt=0;mt<2;mt++)
            #pragma unroll
            for (int nt=0;nt<2;nt++){
                u16 hh[4], ll[4];
                #pragma unroll
                for (int rx=0;rx<4;rx++){
                    float e = __expf(fmaf(a, acc1[mt][nt][rx], bj8[mt*4+rx]));
                    racc[nt] += e;
                    split2(e, hh[rx], ll[rx]);
                }
                int row = nt*16 + ln;                        // i-local (0..31)
                int c4  = jm + mt*16 + quad*4;               // j-local (0..127)
                int off = (row<<7) + ((((c4>>3) ^ (row&15))<<3) | (c4&7));
                *(ushort4*)&elh[buf][off] = make_ushort4(hh[0],hh[1],hh[2],hh[3]);
                *(ushort4*)&ell[buf][off] = make_ushort4(ll[0],ll[1],ll[2],ll[3]);
            }
        __syncthreads();
        // ---- phase B: acc2[c][i] += mu * e^T ----
        #pragma unroll
        for (int ks2=0;ks2<4;ks2++){
            s16x8 B2h[2], B2l[2];
            #pragma unroll
            for (int nt2=0;nt2<2;nt2++){
                int il = nt2*16 + ln;
                int ob = (il<<7) + (((ks2*4+quad) ^ (il&15))<<3);
                B2h[nt2] = ld8(&elh[buf][ob]);
                B2l[nt2] = ld8(&ell[buf][ob]);
            }
            #pragma unroll
            for (int nt2=0;nt2<2;nt2++)
                acc2[nt2] = mm3(A2h[ks2], A2l[ks2], B2h[nt2], B2l[nt2], acc2[nt2]);
        }
    }
    #pragma unroll
    for (int nt=0;nt<2;nt++){
        float v = racc[nt];
        v += __shfl_xor(v,16); v += __shfl_xor(v,32);
        if (quad == 0) rl2[wave][nt*16 + ln] = v;
    }
    __syncthreads();
    #pragma unroll
    for (int nt2=0;nt2<2;nt2++){
        int il = nt2*16 + ln;
        float rinv = __builtin_amdgcn_rcpf(rl2[0][il]+rl2[1][il]+rl2[2][il]+rl2[3][il]);
        #pragma unroll
        for (int rx=0;rx<4;rx++)
            out[((size_t)bg*CD + cm + quad*4 + rx)*HD + i0 + il]
                = acc2[nt2][rx] * rinv;
    }
}

extern "C" void kernel_launch(void* const* d_in, const int* in_sizes, int n_in,
                              void* d_out, int out_size, void* d_ws, size_t ws_size,
                              hipStream_t stream)
{
    (void)in_sizes; (void)n_in; (void)out_size; (void)ws_size;
    const float* q     = (const float*)d_in[0];
    const float* zeta  = (const float*)d_in[1];
    const float* alpha = (const float*)d_in[2];
    const float* mu    = (const float*)d_in[3];
    const float* beta  = (const float*)d_in[4];
    float* out = (float*)d_out;

    const size_t SZ = (size_t)NB*HD*CD;   // elements per tensor
    u16* qTh = (u16*)d_ws;
    u16* qTl = qTh + 1*SZ;
    u16* zTh = qTh + 2*SZ;
    u16* zTl = qTh + 3*SZ;
    u16* qNh = qTh + 4*SZ;
    u16* qNl = qTh + 5*SZ;
    u16* muh = qTh + 6*SZ;
    u16* mul_= qTh + 7*SZ;
    float* bias = (float*)(qTh + 8*SZ);
    float* r    = bias + (size_t)NB*HD;

    dim3 blk(256,1,1);
    int n4 = (int)(SZ/4);
    k_convert  <<<dim3(n4/256), blk, 0, stream>>>(q,  qNh, qNl, n4);
    k_convert  <<<dim3(n4/256), blk, 0, stream>>>(mu, muh, mul_, n4);
    k_transpose<<<dim3(HD/128, NB), blk, 0, stream>>>(q,    qTh, qTl);
    k_transpose<<<dim3(HD/128, NB), blk, 0, stream>>>(zeta, zTh, zTl);
    k_bias     <<<dim3(HD/256, NB), blk, 0, stream>>>(mu, beta, bias);

    k_rowsum<<<dim3(HD/32, NB), blk, 0, stream>>>(qTh,qTl,zTh,zTl,bias,alpha,r);
    k_update<<<dim3(HD/32, NB), blk, 0, stream>>>(qTh,qTl,zTh,zTl,qNh,qNl,bias,alpha,r);
    k_rowsum<<<dim3(HD/32, NB), blk, 0, stream>>>(qTh,qTl,zTh,zTl,bias,alpha,r);
    k_update<<<dim3(HD/32, NB), blk, 0, stream>>>(qTh,qTl,zTh,zTl,qNh,qNl,bias,alpha,r);
    k_final <<<dim3(HD/32, NB), blk, 0, stream>>>(qTh,qTl,zTh,zTl,muh,mul_,bias,alpha,out);
}

// Round 8
// 547.533 us; speedup vs baseline: 1.9369x; 1.1835x over previous
//
#include <hip/hip_runtime.h>

#define NB 16    // N*G
#define CD 64    // C == Cv
#define HD 2048  // H

typedef unsigned short u16;
typedef __attribute__((ext_vector_type(8))) short s16x8;  // 8 bf16 (4 VGPRs)
typedef __attribute__((ext_vector_type(4))) float f32x4;  // MFMA C/D

__device__ __forceinline__ u16 f2bf(float x){
    unsigned u = __float_as_uint(x);
    u += 0x7FFFu + ((u >> 16) & 1u);   // RNE
    return (u16)(u >> 16);
}
__device__ __forceinline__ float bf2f(u16 h){ return __uint_as_float(((unsigned)h) << 16); }
__device__ __forceinline__ void split2(float x, u16& h, u16& l){
    h = f2bf(x); l = f2bf(x - bf2f(h));   // x - hi is exact in fp32
}
union Frag { uint4 q; s16x8 s; };
__device__ __forceinline__ s16x8 ld8(const u16* p){ Frag f; f.q = *(const uint4*)p; return f.s; }
__device__ __forceinline__ f32x4 mfma16(s16x8 a, s16x8 b, f32x4 c){
    return __builtin_amdgcn_mfma_f32_16x16x32_bf16(a, b, c, 0, 0, 0);
}
// fp32-emulating triple MFMA: hi*hi + hi*lo + lo*hi
__device__ __forceinline__ f32x4 mm3(s16x8 ah, s16x8 al, s16x8 bh, s16x8 bl, f32x4 c){
    c = mfma16(ah, bh, c);
    c = mfma16(ah, bl, c);
    c = mfma16(al, bh, c);
    return c;
}
__device__ __forceinline__ f32x4 z4(){ f32x4 v = {0.f,0.f,0.f,0.f}; return v; }

// ---------------- prep kernels (unchanged) ----------------

__global__ void k_convert(const float* __restrict__ src, u16* __restrict__ dh,
                          u16* __restrict__ dl, int n4)
{
    int idx = blockIdx.x*256 + threadIdx.x;
    if (idx >= n4) return;
    float4 v = ((const float4*)src)[idx];
    ushort4 h, l;
    split2(v.x, h.x, l.x); split2(v.y, h.y, l.y);
    split2(v.z, h.z, l.z); split2(v.w, h.w, l.w);
    ((ushort4*)dh)[idx] = h;
    ((ushort4*)dl)[idx] = l;
}

__global__ void k_transpose(const float* __restrict__ src, u16* __restrict__ dh,
                            u16* __restrict__ dl)
{
    int bg = blockIdx.y, h0 = blockIdx.x*128, tid = threadIdx.x;
    __shared__ float ft[CD][132];
    #pragma unroll
    for (int k=0;k<8;k++){
        int flat = tid + 256*k;
        int c = flat >> 5, p = (flat & 31)*4;
        *(float4*)&ft[c][p] = *(const float4*)(src + ((size_t)bg*CD + c)*HD + h0 + p);
    }
    __syncthreads();
    int hl = tid >> 1, c0 = (tid & 1)*32;
    union { u16 u[32]; uint4 q[4]; } oh, ol;
    #pragma unroll
    for (int m=0;m<32;m++){
        float x = ft[c0+m][hl];
        u16 hh; split2(x, hh, ol.u[m]); oh.u[m] = hh;
    }
    size_t base = ((size_t)bg*HD + h0 + hl)*CD + c0;
    #pragma unroll
    for (int t=0;t<4;t++){
        *((uint4*)(dh + base) + t) = oh.q[t];
        *((uint4*)(dl + base) + t) = ol.q[t];
    }
}

__global__ void k_bias(const float* __restrict__ mu, const float* __restrict__ beta,
                       float* __restrict__ bias)
{
    int bg = blockIdx.y;
    int j  = blockIdx.x*256 + threadIdx.x;
    const float* m = mu + (size_t)bg*CD*HD + j;
    float s = 0.f;
    #pragma unroll
    for (int c=0;c<CD;c++){ float v = m[(size_t)c*HD]; s = fmaf(v, v, s); }
    bias[(size_t)bg*HD + j] = 0.5f * beta[0] * s;
}

// ---------------- k_rowsum: j-split halves; grid (64, NB) = 1024 blocks ----------------
// (256,2): allocator's 128-VGPR bucket (no spill); HW packs 4 blocks/CU from resources.
__global__ __launch_bounds__(256,2) void k_rowsum(
    const u16* __restrict__ qTh, const u16* __restrict__ qTl,
    const u16* __restrict__ zTh, const u16* __restrict__ zTl,
    const float* __restrict__ bias, const float* __restrict__ alpha,
    float* __restrict__ r0, float* __restrict__ r1)
{
    const int bg = blockIdx.y, i0 = (blockIdx.x & 31)*64, jh = blockIdx.x >> 5;
    const int JB = jh*1024;
    float* rout = jh ? r1 : r0;
    const int tid = threadIdx.x, wave = tid>>6, lane = tid&63, ln = lane&15, quad = lane>>4;
    const int jw = wave*32;
    const float a = alpha[0];
    __shared__ float rpart[4][64];

    s16x8 Ah[4][2], Al[4][2];     // resident q^T frags: rows i0..i0+63
    #pragma unroll
    for (int mt=0;mt<4;mt++)
        #pragma unroll
        for (int ks=0;ks<2;ks++){
            size_t off = ((size_t)bg*HD + i0 + mt*16 + ln)*CD + ks*32 + quad*8;
            Ah[mt][ks] = ld8(qTh + off);
            Al[mt][ks] = ld8(qTl + off);
        }
    float racc[16];
    #pragma unroll
    for (int k=0;k<16;k++) racc[k] = 0.f;
    const float* bb = bias + (size_t)bg*HD + JB;

    s16x8 B0h[2][2], B0l[2][2], B1h[2][2], B1l[2][2];
    float bj0[2], bj1[2];

    // prologue: tile 0
    #pragma unroll
    for (int nt=0;nt<2;nt++){
        #pragma unroll
        for (int ks=0;ks<2;ks++){
            size_t off = ((size_t)bg*HD + JB + jw + nt*16 + ln)*CD + ks*32 + quad*8;
            B0h[nt][ks] = ld8(zTh + off);
            B0l[nt][ks] = ld8(zTl + off);
        }
        bj0[nt] = bb[jw + nt*16 + ln];
    }

    for (int j0=0;j0<1024;j0+=256){
        #pragma unroll
        for (int nt=0;nt<2;nt++){
            #pragma unroll
            for (int ks=0;ks<2;ks++){
                size_t off = ((size_t)bg*HD + JB + j0+128 + jw + nt*16 + ln)*CD + ks*32 + quad*8;
                B1h[nt][ks] = ld8(zTh + off);
                B1l[nt][ks] = ld8(zTl + off);
            }
            bj1[nt] = bb[j0+128 + jw + nt*16 + ln];
        }
        {
            f32x4 acc[4][2];
            #pragma unroll
            for (int mt=0;mt<4;mt++){ acc[mt][0]=z4(); acc[mt][1]=z4(); }
            #pragma unroll
            for (int ks=0;ks<2;ks++)
                #pragma unroll
                for (int mt=0;mt<4;mt++)
                    #pragma unroll
                    for (int nt=0;nt<2;nt++)
                        acc[mt][nt] = mm3(Ah[mt][ks], Al[mt][ks], B0h[nt][ks], B0l[nt][ks], acc[mt][nt]);
            #pragma unroll
            for (int mt=0;mt<4;mt++)
                #pragma unroll
                for (int nt=0;nt<2;nt++)
                    #pragma unroll
                    for (int rx=0;rx<4;rx++)
                        racc[mt*4+rx] += __expf(fmaf(a, acc[mt][nt][rx], bj0[nt]));
        }
        {
            int jn2 = (j0+256) & 1023;
            #pragma unroll
            for (int nt=0;nt<2;nt++){
                #pragma unroll
                for (int ks=0;ks<2;ks++){
                    size_t off = ((size_t)bg*HD + JB + jn2 + jw + nt*16 + ln)*CD + ks*32 + quad*8;
                    B0h[nt][ks] = ld8(zTh + off);
                    B0l[nt][ks] = ld8(zTl + off);
                }
                bj0[nt] = bb[jn2 + jw + nt*16 + ln];
            }
        }
        {
            f32x4 acc[4][2];
            #pragma unroll
            for (int mt=0;mt<4;mt++){ acc[mt][0]=z4(); acc[mt][1]=z4(); }
            #pragma unroll
            for (int ks=0;ks<2;ks++)
                #pragma unroll
                for (int mt=0;mt<4;mt++)
                    #pragma unroll
                    for (int nt=0;nt<2;nt++)
                        acc[mt][nt] = mm3(Ah[mt][ks], Al[mt][ks], B1h[nt][ks], B1l[nt][ks], acc[mt][nt]);
            #pragma unroll
            for (int mt=0;mt<4;mt++)
                #pragma unroll
                for (int nt=0;nt<2;nt++)
                    #pragma unroll
                    for (int rx=0;rx<4;rx++)
                        racc[mt*4+rx] += __expf(fmaf(a, acc[mt][nt][rx], bj1[nt]));
        }
    }
    #pragma unroll
    for (int k=0;k<16;k++){
        float v = racc[k];
        v += __shfl_xor(v,1); v += __shfl_xor(v,2);
        v += __shfl_xor(v,4); v += __shfl_xor(v,8);
        racc[k] = v;
    }
    if (ln == 0){
        #pragma unroll
        for (int mt=0;mt<4;mt++)
            #pragma unroll
            for (int rx=0;rx<4;rx++)
                rpart[wave][mt*16 + quad*4 + rx] = racc[mt*4+rx];
    }
    __syncthreads();
    if (tid < 64)
        rout[(size_t)bg*HD + i0 + tid] = rpart[0][tid]+rpart[1][tid]+rpart[2][tid]+rpart[3][tid];
}

// ---------------- k_update: i-split halves; grid (64, NB); partial num/den out ----------------
// Block: 64 j-cols, sweeps its i-half (8 steps of 128). Single-buffer LDS w-tile (33 KB).
// (256,2): 128-VGPR bucket, no spill; HW packs 4 blocks/CU (VGPR 128, LDS 33 KB, grid 1024).
__global__ __launch_bounds__(256,2) void k_update(
    const u16* __restrict__ qTh, const u16* __restrict__ qTl,
    const u16* __restrict__ zTh, const u16* __restrict__ zTl,
    const u16* __restrict__ qNh, const u16* __restrict__ qNl,
    const float* __restrict__ bias, const float* __restrict__ alpha,
    const float* __restrict__ r0, const float* __restrict__ r1,
    float* __restrict__ numP, float* __restrict__ denP)
{
    const int bg = blockIdx.y, j0 = (blockIdx.x & 31)*64, ih = blockIdx.x >> 5;
    const int IB = ih << 10;
    const int tid = threadIdx.x, wave = tid>>6, lane = tid&63, ln = lane&15, quad = lane>>4;
    const int cm = (wave&1)*32, jn = (wave>>1)*32;
    const float a = alpha[0];
    __shared__ __align__(16) u16 wlh[64*128], wll[64*128];   // w^T tile [j][i], swizzled
    __shared__ float denl[4][64];

    s16x8 Bh[4][2], Bl[4][2];     // resident z^T frags: rows j0..j0+63 (read-only now)
    #pragma unroll
    for (int nt=0;nt<4;nt++)
        #pragma unroll
        for (int ks=0;ks<2;ks++){
            size_t off = ((size_t)bg*HD + j0 + nt*16 + ln)*CD + ks*32 + quad*8;
            Bh[nt][ks] = ld8(zTh + off);
            Bl[nt][ks] = ld8(zTl + off);
        }
    float bj[4];
    #pragma unroll
    for (int nt=0;nt<4;nt++) bj[nt] = bias[(size_t)bg*HD + j0 + nt*16 + ln];

    f32x4 acc2[2][2] = {{z4(),z4()},{z4(),z4()}};
    float den[4] = {0.f,0.f,0.f,0.f};

    for (int t=0; t<8; ++t){
        const int is = IB + t*128;
        // ---- phase-A operand loads (q^T) ----
        s16x8 Ah[2][2], Al[2][2];
        #pragma unroll
        for (int ks=0;ks<2;ks++)
            #pragma unroll
            for (int mt=0;mt<2;mt++){
                size_t off = ((size_t)bg*HD + is + wave*32 + mt*16 + ln)*CD + ks*32 + quad*8;
                Ah[mt][ks] = ld8(qTh + off);
                Al[mt][ks] = ld8(qTl + off);
            }
        // ---- first half of phase-B operand loads (qN, ks2=0,1) ----
        s16x8 A2h[4][2], A2l[4][2];
        #pragma unroll
        for (int ks2=0;ks2<2;ks2++)
            #pragma unroll
            for (int mtN=0;mtN<2;mtN++){
                size_t off = ((size_t)bg*CD + cm + mtN*16 + ln)*HD + is + ks2*32 + quad*8;
                A2h[ks2][mtN] = ld8(qNh + off);
                A2l[ks2][mtN] = ld8(qNl + off);
            }
        // ---- r loads (r = r0+r1 partials) ----
        float ri[8];
        #pragma unroll
        for (int mt=0;mt<2;mt++){
            size_t ro = (size_t)bg*HD + is + wave*32 + mt*16 + quad*4;
            float4 ra = *(const float4*)&r0[ro];
            float4 rb = *(const float4*)&r1[ro];
            ri[mt*4+0] = __builtin_amdgcn_rcpf(ra.x+rb.x);
            ri[mt*4+1] = __builtin_amdgcn_rcpf(ra.y+rb.y);
            ri[mt*4+2] = __builtin_amdgcn_rcpf(ra.z+rb.z);
            ri[mt*4+3] = __builtin_amdgcn_rcpf(ra.w+rb.w);
        }
        // ---- phase A MFMA ----
        f32x4 acc1[2][4];
        #pragma unroll
        for (int mt=0;mt<2;mt++)
            #pragma unroll
            for (int nt=0;nt<4;nt++) acc1[mt][nt] = z4();
        #pragma unroll
        for (int ks=0;ks<2;ks++)
            #pragma unroll
            for (int mt=0;mt<2;mt++)
                #pragma unroll
                for (int nt=0;nt<4;nt++)
                    acc1[mt][nt] = mm3(Ah[mt][ks], Al[mt][ks], Bh[nt][ks], Bl[nt][ks], acc1[mt][nt]);
        // ---- second half of phase-B loads (qN, ks2=2,3) ----
        #pragma unroll
        for (int ks2=2;ks2<4;ks2++)
            #pragma unroll
            for (int mtN=0;mtN<2;mtN++){
                size_t off = ((size_t)bg*CD + cm + mtN*16 + ln)*HD + is + ks2*32 + quad*8;
                A2h[ks2][mtN] = ld8(qNh + off);
                A2l[ks2][mtN] = ld8(qNl + off);
            }
        __syncthreads();   // previous step's phase-B LDS reads complete
        // ---- w compute + LDS write ----
        #pragma unroll
        for (int mt=0;mt<2;mt++)
            #pragma unroll
            for (int nt=0;nt<4;nt++){
                u16 hh[4], ll[4];
                #pragma unroll
                for (int rx=0;rx<4;rx++){
                    float w = __expf(fmaf(a, acc1[mt][nt][rx], bj[nt])) * ri[mt*4+rx];
                    den[nt] += w;
                    split2(w, hh[rx], ll[rx]);
                }
                int row = nt*16 + ln;                        // j-local
                int c4  = wave*32 + mt*16 + quad*4;          // i-local
                int off = (row<<7) + ((((c4>>3) ^ (row&15))<<3) | (c4&7));
                *(ushort4*)&wlh[off] = make_ushort4(hh[0],hh[1],hh[2],hh[3]);
                *(ushort4*)&wll[off] = make_ushort4(ll[0],ll[1],ll[2],ll[3]);
            }
        __syncthreads();
        // ---- phase B: LDS reads + MFMA ----
        #pragma unroll
        for (int ks2=0;ks2<4;ks2++){
            s16x8 B2h[2], B2l[2];
            #pragma unroll
            for (int nt2=0;nt2<2;nt2++){
                int jl = jn + nt2*16 + ln;
                int ob = (jl<<7) + (((ks2*4+quad) ^ (jl&15))<<3);
                B2h[nt2] = ld8(&wlh[ob]);
                B2l[nt2] = ld8(&wll[ob]);
            }
            #pragma unroll
            for (int mtN=0;mtN<2;mtN++)
                #pragma unroll
                for (int nt2=0;nt2<2;nt2++)
                    acc2[mtN][nt2] = mm3(A2h[ks2][mtN], A2l[ks2][mtN], B2h[nt2], B2l[nt2], acc2[mtN][nt2]);
        }
    }
    // den partial reduce + store
    #pragma unroll
    for (int nt=0;nt<4;nt++){
        float v = den[nt];
        v += __shfl_xor(v,16); v += __shfl_xor(v,32);
        if (quad == 0) denl[wave][nt*16 + ln] = v;
    }
    __syncthreads();
    if (tid < 64)
        denP[((size_t)ih*NB + bg)*HD + j0 + tid]
            = denl[0][tid]+denl[1][tid]+denl[2][tid]+denl[3][tid];
    // num partial store (f32)
    #pragma unroll
    for (int nt2=0;nt2<2;nt2++){
        int jl = jn + nt2*16 + ln;
        #pragma unroll
        for (int mtN=0;mtN<2;mtN++){
            size_t off = (size_t)ih*NB*HD*CD
                       + ((size_t)bg*HD + j0 + jl)*CD + cm + mtN*16 + quad*4;
            *(float4*)&numP[off] = *(float4*)&acc2[mtN][nt2];
        }
    }
}

// zeta = num/den, split2, write z^T (layout [bg][j][c] == flat num layout)
__global__ void k_zcomb(const float* __restrict__ numP, const float* __restrict__ denP,
                        u16* __restrict__ zTh, u16* __restrict__ zTl)
{
    size_t f = ((size_t)blockIdx.x*256 + threadIdx.x) * 4;
    size_t jg = f >> 6;                       // bg*HD + j
    float4 n0 = *(const float4*)&numP[f];
    float4 n1 = *(const float4*)&numP[(size_t)NB*HD*CD + f];
    float di = __builtin_amdgcn_rcpf(denP[jg] + denP[(size_t)NB*HD + jg]);
    ushort4 h, l;
    split2((n0.x+n1.x)*di, h.x, l.x);
    split2((n0.y+n1.y)*di, h.y, l.y);
    split2((n0.z+n1.z)*di, h.z, l.z);
    split2((n0.w+n1.w)*di, h.w, l.w);
    *(ushort4*)&zTh[f] = h;
    *(ushort4*)&zTl[f] = l;
}

// ---------------- k_final: j-split halves; grid (64, NB); partial num/r out ----------------
__global__ __launch_bounds__(256,2) void k_final(
    const u16* __restrict__ qTh, const u16* __restrict__ qTl,
    const u16* __restrict__ zTh, const u16* __restrict__ zTl,
    const u16* __restrict__ muh, const u16* __restrict__ mul_,
    const float* __restrict__ bias, const float* __restrict__ alpha,
    float* __restrict__ numP, float* __restrict__ rP)
{
    const int bg = blockIdx.y, i0 = (blockIdx.x & 31)*64, jh = blockIdx.x >> 5;
    const int JB = jh << 10;
    const int tid = threadIdx.x, wave = tid>>6, lane = tid&63, ln = lane&15, quad = lane>>4;
    const int cm = (wave&1)*32, in_ = (wave>>1)*32;
    const float a = alpha[0];
    __shared__ __align__(16) u16 elh[64*128], ell[64*128];   // e^T tile [i][j], swizzled
    __shared__ float rl2[4][64];

    s16x8 Bh[4][2], Bl[4][2];     // resident q^T frags: rows i0..i0+63 (n operand)
    #pragma unroll
    for (int nt=0;nt<4;nt++)
        #pragma unroll
        for (int ks=0;ks<2;ks++){
            size_t off = ((size_t)bg*HD + i0 + nt*16 + ln)*CD + ks*32 + quad*8;
            Bh[nt][ks] = ld8(qTh + off);
            Bl[nt][ks] = ld8(qTl + off);
        }
    f32x4 acc2[2][2] = {{z4(),z4()},{z4(),z4()}};
    float racc[4] = {0.f,0.f,0.f,0.f};

    for (int t=0; t<8; ++t){
        const int js = JB + t*128;
        // ---- phase-A operand loads (z^T) ----
        s16x8 Ah[2][2], Al[2][2];
        #pragma unroll
        for (int ks=0;ks<2;ks++)
            #pragma unroll
            for (int mt=0;mt<2;mt++){
                size_t off = ((size_t)bg*HD + js + wave*32 + mt*16 + ln)*CD + ks*32 + quad*8;
                Ah[mt][ks] = ld8(zTh + off);
                Al[mt][ks] = ld8(zTl + off);
            }
        // ---- first half of phase-B operand loads (mu, ks2=0,1) ----
        s16x8 A2h[4][2], A2l[4][2];
        #pragma unroll
        for (int ks2=0;ks2<2;ks2++)
            #pragma unroll
            for (int mtN=0;mtN<2;mtN++){
                size_t off = ((size_t)bg*CD + cm + mtN*16 + ln)*HD + js + ks2*32 + quad*8;
                A2h[ks2][mtN] = ld8(muh + off);
                A2l[ks2][mtN] = ld8(mul_ + off);
            }
        // ---- bias loads (vectorized) ----
        float bj8[8];
        #pragma unroll
        for (int mt=0;mt<2;mt++){
            float4 bv = *(const float4*)&bias[(size_t)bg*HD + js + wave*32 + mt*16 + quad*4];
            bj8[mt*4+0]=bv.x; bj8[mt*4+1]=bv.y; bj8[mt*4+2]=bv.z; bj8[mt*4+3]=bv.w;
        }
        // ---- phase A MFMA: S'[j][i] (m = j, n = i) ----
        f32x4 acc1[2][4];
        #pragma unroll
        for (int mt=0;mt<2;mt++)
            #pragma unroll
            for (int nt=0;nt<4;nt++) acc1[mt][nt] = z4();
        #pragma unroll
        for (int ks=0;ks<2;ks++)
            #pragma unroll
            for (int mt=0;mt<2;mt++)
                #pragma unroll
                for (int nt=0;nt<4;nt++)
                    acc1[mt][nt] = mm3(Ah[mt][ks], Al[mt][ks], Bh[nt][ks], Bl[nt][ks], acc1[mt][nt]);
        // ---- second half of phase-B loads (mu, ks2=2,3) ----
        #pragma unroll
        for (int ks2=2;ks2<4;ks2++)
            #pragma unroll
            for (int mtN=0;mtN<2;mtN++){
                size_t off = ((size_t)bg*CD + cm + mtN*16 + ln)*HD + js + ks2*32 + quad*8;
                A2h[ks2][mtN] = ld8(muh + off);
                A2l[ks2][mtN] = ld8(mul_ + off);
            }
        __syncthreads();   // previous step's phase-B LDS reads complete
        // ---- e compute + LDS write ----
        #pragma unroll
        for (int mt=0;mt<2;mt++)
            #pragma unroll
            for (int nt=0;nt<4;nt++){
                u16 hh[4], ll[4];
                #pragma unroll
                for (int rx=0;rx<4;rx++){
                    float e = __expf(fmaf(a, acc1[mt][nt][rx], bj8[mt*4+rx]));
                    racc[nt] += e;
                    split2(e, hh[rx], ll[rx]);
                }
                int row = nt*16 + ln;                        // i-local
                int c4  = wave*32 + mt*16 + quad*4;          // j-local
                int off = (row<<7) + ((((c4>>3) ^ (row&15))<<3) | (c4&7));
                *(ushort4*)&elh[off] = make_ushort4(hh[0],hh[1],hh[2],hh[3]);
                *(ushort4*)&ell[off] = make_ushort4(ll[0],ll[1],ll[2],ll[3]);
            }
        __syncthreads();
        // ---- phase B: acc2[c][i] += mu * e^T ----
        #pragma unroll
        for (int ks2=0;ks2<4;ks2++){
            s16x8 B2h[2], B2l[2];
            #pragma unroll
            for (int nt2=0;nt2<2;nt2++){
                int il = in_ + nt2*16 + ln;
                int ob = (il<<7) + (((ks2*4+quad) ^ (il&15))<<3);
                B2h[nt2] = ld8(&elh[ob]);
                B2l[nt2] = ld8(&ell[ob]);
            }
            #pragma unroll
            for (int mtN=0;mtN<2;mtN++)
                #pragma unroll
                for (int nt2=0;nt2<2;nt2++)
                    acc2[mtN][nt2] = mm3(A2h[ks2][mtN], A2l[ks2][mtN], B2h[nt2], B2l[nt2], acc2[mtN][nt2]);
        }
    }
    // r partial reduce + store
    #pragma unroll
    for (int nt=0;nt<4;nt++){
        float v = racc[nt];
        v += __shfl_xor(v,16); v += __shfl_xor(v,32);
        if (quad == 0) rl2[wave][nt*16 + ln] = v;
    }
    __syncthreads();
    if (tid < 64)
        rP[((size_t)jh*NB + bg)*HD + i0 + tid]
            = rl2[0][tid]+rl2[1][tid]+rl2[2][tid]+rl2[3][tid];
    // num partial store (f32, out layout)
    #pragma unroll
    for (int nt2=0;nt2<2;nt2++){
        int il = in_ + nt2*16 + ln;
        #pragma unroll
        for (int mtN=0;mtN<2;mtN++)
            #pragma unroll
            for (int rx=0;rx<4;rx++)
                numP[(size_t)jh*NB*HD*CD
                     + ((size_t)bg*CD + cm + mtN*16 + quad*4 + rx)*HD + i0 + il]
                    = acc2[mtN][nt2][rx];
    }
}

// out = num/r  (layout [bg][c][i] == flat num layout)
__global__ void k_ocomb(const float* __restrict__ numP, const float* __restrict__ rP,
                        float* __restrict__ out)
{
    size_t f = ((size_t)blockIdx.x*256 + threadIdx.x) * 4;
    size_t bg = f >> 17;                      // CD*HD = 1<<17
    size_t ibase = (bg << 11) + (f & (HD-1));
    float4 n0 = *(const float4*)&numP[f];
    float4 n1 = *(const float4*)&numP[(size_t)NB*HD*CD + f];
    float4 ra = *(const float4*)&rP[ibase];
    float4 rb = *(const float4*)&rP[(size_t)NB*HD + ibase];
    float4 o;
    o.x = (n0.x+n1.x)*__builtin_amdgcn_rcpf(ra.x+rb.x);
    o.y = (n0.y+n1.y)*__builtin_amdgcn_rcpf(ra.y+rb.y);
    o.z = (n0.z+n1.z)*__builtin_amdgcn_rcpf(ra.z+rb.z);
    o.w = (n0.w+n1.w)*__builtin_amdgcn_rcpf(ra.w+rb.w);
    *(float4*)&out[f] = o;
}

extern "C" void kernel_launch(void* const* d_in, const int* in_sizes, int n_in,
                              void* d_out, int out_size, void* d_ws, size_t ws_size,
                              hipStream_t stream)
{
    (void)in_sizes; (void)n_in; (void)out_size; (void)ws_size;
    const float* q     = (const float*)d_in[0];
    const float* zeta  = (const float*)d_in[1];
    const float* alpha = (const float*)d_in[2];
    const float* mu    = (const float*)d_in[3];
    const float* beta  = (const float*)d_in[4];
    float* out = (float*)d_out;

    const size_t SZ = (size_t)NB*HD*CD;   // elements per tensor (2M)
    u16* qTh = (u16*)d_ws;
    u16* qTl = qTh + 1*SZ;
    u16* zTh = qTh + 2*SZ;
    u16* zTl = qTh + 3*SZ;
    u16* qNh = qTh + 4*SZ;
    u16* qNl = qTh + 5*SZ;
    u16* muh = qTh + 6*SZ;
    u16* mul_= qTh + 7*SZ;
    float* bias = (float*)(qTh + 8*SZ);
    float* r0   = bias + (size_t)NB*HD;
    float* r1   = r0   + (size_t)NB*HD;
    float* denP = r1   + (size_t)NB*HD;          // [2][NB*HD]
    float* rP   = denP + (size_t)2*NB*HD;        // [2][NB*HD]
    float* numP = rP   + (size_t)2*NB*HD;        // [2][SZ] f32 (reused update->final)

    dim3 blk(256,1,1);
    int n4 = (int)(SZ/4);
    k_convert  <<<dim3(n4/256), blk, 0, stream>>>(q,  qNh, qNl, n4);
    k_convert  <<<dim3(n4/256), blk, 0, stream>>>(mu, muh, mul_, n4);
    k_transpose<<<dim3(HD/128, NB), blk, 0, stream>>>(q,    qTh, qTl);
    k_transpose<<<dim3(HD/128, NB), blk, 0, stream>>>(zeta, zTh, zTl);
    k_bias     <<<dim3(HD/256, NB), blk, 0, stream>>>(mu, beta, bias);

    k_rowsum<<<dim3(64, NB), blk, 0, stream>>>(qTh,qTl,zTh,zTl,bias,alpha,r0,r1);
    k_update<<<dim3(64, NB), blk, 0, stream>>>(qTh,qTl,zTh,zTl,qNh,qNl,bias,alpha,r0,r1,numP,denP);
    k_zcomb <<<dim3((int)(SZ/4/256)), blk, 0, stream>>>(numP,denP,zTh,zTl);
    k_rowsum<<<dim3(64, NB), blk, 0, stream>>>(qTh,qTl,zTh,zTl,bias,alpha,r0,r1);
    k_update<<<dim3(64, NB), blk, 0, stream>>>(qTh,qTl,zTh,zTl,qNh,qNl,bias,alpha,r0,r1,numP,denP);
    k_zcomb <<<dim3((int)(SZ/4/256)), blk, 0, stream>>>(numP,denP,zTh,zTl);
    k_final <<<dim3(64, NB), blk, 0, stream>>>(qTh,qTl,zTh,zTl,muh,mul_,bias,alpha,numP,rP);
    k_ocomb <<<dim3((int)(SZ/4/256)), blk, 0, stream>>>(numP,rP,out);
}

// Round 9
// 501.426 us; speedup vs baseline: 2.1150x; 1.0920x over previous
//
#include <hip/hip_runtime.h>

#define NB 16    // N*G
#define CD 64    // C == Cv
#define HD 2048  // H

typedef unsigned short u16;
typedef __attribute__((ext_vector_type(8))) short s16x8;  // 8 bf16 (4 VGPRs)
typedef __attribute__((ext_vector_type(4))) float f32x4;  // MFMA C/D

__device__ __forceinline__ u16 f2bf(float x){
    unsigned u = __float_as_uint(x);
    u += 0x7FFFu + ((u >> 16) & 1u);   // RNE
    return (u16)(u >> 16);
}
__device__ __forceinline__ float bf2f(u16 h){ return __uint_as_float(((unsigned)h) << 16); }
__device__ __forceinline__ void split2(float x, u16& h, u16& l){
    h = f2bf(x); l = f2bf(x - bf2f(h));   // x - hi is exact in fp32
}
union Frag { uint4 q; s16x8 s; };
__device__ __forceinline__ s16x8 ld8(const u16* p){ Frag f; f.q = *(const uint4*)p; return f.s; }
__device__ __forceinline__ f32x4 mfma16(s16x8 a, s16x8 b, f32x4 c){
    return __builtin_amdgcn_mfma_f32_16x16x32_bf16(a, b, c, 0, 0, 0);
}
// fp32-emulating triple MFMA: hi*hi + hi*lo + lo*hi
__device__ __forceinline__ f32x4 mm3(s16x8 ah, s16x8 al, s16x8 bh, s16x8 bl, f32x4 c){
    c = mfma16(ah, bh, c);
    c = mfma16(ah, bl, c);
    c = mfma16(al, bh, c);
    return c;
}
__device__ __forceinline__ f32x4 z4(){ f32x4 v = {0.f,0.f,0.f,0.f}; return v; }

// ---------------- prep kernels (unchanged) ----------------

__global__ void k_convert(const float* __restrict__ src, u16* __restrict__ dh,
                          u16* __restrict__ dl, int n4)
{
    int idx = blockIdx.x*256 + threadIdx.x;
    if (idx >= n4) return;
    float4 v = ((const float4*)src)[idx];
    ushort4 h, l;
    split2(v.x, h.x, l.x); split2(v.y, h.y, l.y);
    split2(v.z, h.z, l.z); split2(v.w, h.w, l.w);
    ((ushort4*)dh)[idx] = h;
    ((ushort4*)dl)[idx] = l;
}

__global__ void k_transpose(const float* __restrict__ src, u16* __restrict__ dh,
                            u16* __restrict__ dl)
{
    int bg = blockIdx.y, h0 = blockIdx.x*128, tid = threadIdx.x;
    __shared__ float ft[CD][132];
    #pragma unroll
    for (int k=0;k<8;k++){
        int flat = tid + 256*k;
        int c = flat >> 5, p = (flat & 31)*4;
        *(float4*)&ft[c][p] = *(const float4*)(src + ((size_t)bg*CD + c)*HD + h0 + p);
    }
    __syncthreads();
    int hl = tid >> 1, c0 = (tid & 1)*32;
    union { u16 u[32]; uint4 q[4]; } oh, ol;
    #pragma unroll
    for (int m=0;m<32;m++){
        float x = ft[c0+m][hl];
        u16 hh; split2(x, hh, ol.u[m]); oh.u[m] = hh;
    }
    size_t base = ((size_t)bg*HD + h0 + hl)*CD + c0;
    #pragma unroll
    for (int t=0;t<4;t++){
        *((uint4*)(dh + base) + t) = oh.q[t];
        *((uint4*)(dl + base) + t) = ol.q[t];
    }
}

__global__ void k_bias(const float* __restrict__ mu, const float* __restrict__ beta,
                       float* __restrict__ bias)
{
    int bg = blockIdx.y;
    int j  = blockIdx.x*256 + threadIdx.x;
    const float* m = mu + (size_t)bg*CD*HD + j;
    float s = 0.f;
    #pragma unroll
    for (int c=0;c<CD;c++){ float v = m[(size_t)c*HD]; s = fmaf(v, v, s); }
    bias[(size_t)bg*HD + j] = 0.5f * beta[0] * s;
}

// ---------------- main MFMA kernels ----------------
// Residency is pinned at 2 waves/SIMD (total arch+acc regs ~190; r7/r8 evidence), so
// per-wave budget is ~256 regs: prefetch is free IF it survives the scheduler.
// sched_barrier(0) pins the load block above the MFMA phase (loads can't sink);
// setprio(1) biases the CU scheduler toward the MFMA-issuing wave while the sibling
// block's wave (phase-shifted) issues its loads.

// r[i] = sum_j exp(a*S+bias_j). Block: 64 i-rows, waves split j; B tile double-buffered
// in registers; prefetch pinned with sched_barrier.
__global__ __launch_bounds__(256,2) void k_rowsum(
    const u16* __restrict__ qTh, const u16* __restrict__ qTl,
    const u16* __restrict__ zTh, const u16* __restrict__ zTl,
    const float* __restrict__ bias, const float* __restrict__ alpha,
    float* __restrict__ r)
{
    const int bg = blockIdx.y, i0 = blockIdx.x*64;
    const int tid = threadIdx.x, wave = tid>>6, lane = tid&63, ln = lane&15, quad = lane>>4;
    const int jw = wave*32;
    const float a = alpha[0];
    __shared__ float rpart[4][64];

    s16x8 Ah[4][2], Al[4][2];     // resident q^T frags: rows i0..i0+63
    #pragma unroll
    for (int mt=0;mt<4;mt++)
        #pragma unroll
        for (int ks=0;ks<2;ks++){
            size_t off = ((size_t)bg*HD + i0 + mt*16 + ln)*CD + ks*32 + quad*8;
            Ah[mt][ks] = ld8(qTh + off);
            Al[mt][ks] = ld8(qTl + off);
        }
    float racc[16];
    #pragma unroll
    for (int k=0;k<16;k++) racc[k] = 0.f;
    const float* bb = bias + (size_t)bg*HD;

    s16x8 B0h[2][2], B0l[2][2], B1h[2][2], B1l[2][2];
    float bj0[2], bj1[2];

    // prologue: tile 0
    #pragma unroll
    for (int nt=0;nt<2;nt++){
        #pragma unroll
        for (int ks=0;ks<2;ks++){
            size_t off = ((size_t)bg*HD + jw + nt*16 + ln)*CD + ks*32 + quad*8;
            B0h[nt][ks] = ld8(zTh + off);
            B0l[nt][ks] = ld8(zTl + off);
        }
        bj0[nt] = bb[jw + nt*16 + ln];
    }

    for (int j0=0;j0<HD;j0+=256){
        // issue loads for tile j0+128 into B1, pinned above the B0 compute
        #pragma unroll
        for (int nt=0;nt<2;nt++){
            #pragma unroll
            for (int ks=0;ks<2;ks++){
                size_t off = ((size_t)bg*HD + j0+128 + jw + nt*16 + ln)*CD + ks*32 + quad*8;
                B1h[nt][ks] = ld8(zTh + off);
                B1l[nt][ks] = ld8(zTl + off);
            }
            bj1[nt] = bb[j0+128 + jw + nt*16 + ln];
        }
        __builtin_amdgcn_sched_barrier(0);
        // compute tile j0 with B0
        {
            f32x4 acc[4][2];
            #pragma unroll
            for (int mt=0;mt<4;mt++){ acc[mt][0]=z4(); acc[mt][1]=z4(); }
            __builtin_amdgcn_s_setprio(1);
            #pragma unroll
            for (int ks=0;ks<2;ks++)
                #pragma unroll
                for (int mt=0;mt<4;mt++)
                    #pragma unroll
                    for (int nt=0;nt<2;nt++)
                        acc[mt][nt] = mm3(Ah[mt][ks], Al[mt][ks], B0h[nt][ks], B0l[nt][ks], acc[mt][nt]);
            __builtin_amdgcn_s_setprio(0);
            #pragma unroll
            for (int mt=0;mt<4;mt++)
                #pragma unroll
                for (int nt=0;nt<2;nt++)
                    #pragma unroll
                    for (int rx=0;rx<4;rx++)
                        racc[mt*4+rx] += __expf(fmaf(a, acc[mt][nt][rx], bj0[nt]));
        }
        // issue loads for tile (j0+256)&(HD-1) into B0, pinned above the B1 compute
        {
            int jn2 = (j0+256) & (HD-1);
            #pragma unroll
            for (int nt=0;nt<2;nt++){
                #pragma unroll
                for (int ks=0;ks<2;ks++){
                    size_t off = ((size_t)bg*HD + jn2 + jw + nt*16 + ln)*CD + ks*32 + quad*8;
                    B0h[nt][ks] = ld8(zTh + off);
                    B0l[nt][ks] = ld8(zTl + off);
                }
                bj0[nt] = bb[jn2 + jw + nt*16 + ln];
            }
        }
        __builtin_amdgcn_sched_barrier(0);
        // compute tile j0+128 with B1
        {
            f32x4 acc[4][2];
            #pragma unroll
            for (int mt=0;mt<4;mt++){ acc[mt][0]=z4(); acc[mt][1]=z4(); }
            __builtin_amdgcn_s_setprio(1);
            #pragma unroll
            for (int ks=0;ks<2;ks++)
                #pragma unroll
                for (int mt=0;mt<4;mt++)
                    #pragma unroll
                    for (int nt=0;nt<2;nt++)
                        acc[mt][nt] = mm3(Ah[mt][ks], Al[mt][ks], B1h[nt][ks], B1l[nt][ks], acc[mt][nt]);
            __builtin_amdgcn_s_setprio(0);
            #pragma unroll
            for (int mt=0;mt<4;mt++)
                #pragma unroll
                for (int nt=0;nt<2;nt++)
                    #pragma unroll
                    for (int rx=0;rx<4;rx++)
                        racc[mt*4+rx] += __expf(fmaf(a, acc[mt][nt][rx], bj1[nt]));
        }
    }
    #pragma unroll
    for (int k=0;k<16;k++){
        float v = racc[k];
        v += __shfl_xor(v,1); v += __shfl_xor(v,2);
        v += __shfl_xor(v,4); v += __shfl_xor(v,8);
        racc[k] = v;
    }
    if (ln == 0){
        #pragma unroll
        for (int mt=0;mt<4;mt++)
            #pragma unroll
            for (int rx=0;rx<4;rx++)
                rpart[wave][mt*16 + quad*4 + rx] = racc[mt*4+rx];
    }
    __syncthreads();
    if (tid < 64)
        r[(size_t)bg*HD + i0 + tid] = rpart[0][tid]+rpart[1][tid]+rpart[2][tid]+rpart[3][tid];
}

// zeta update. Block: 64 j-cols, sweeps i (128/step). ALL global operands for the step
// issued at top and PINNED with sched_barrier; LDS w-tile double-buffered (1 barrier).
__global__ __launch_bounds__(256,2) void k_update(
    const u16* __restrict__ qTh, const u16* __restrict__ qTl,
    u16* zTh, u16* zTl,                               // read then overwritten (own rows only)
    const u16* __restrict__ qNh, const u16* __restrict__ qNl,
    const float* __restrict__ bias, const float* __restrict__ alpha,
    const float* __restrict__ r)
{
    const int bg = blockIdx.y, j0 = blockIdx.x*64;
    const int tid = threadIdx.x, wave = tid>>6, lane = tid&63, ln = lane&15, quad = lane>>4;
    const int cm = (wave&1)*32, jn = (wave>>1)*32;
    const float a = alpha[0];
    __shared__ u16 wlh[2][64*128], wll[2][64*128];    // double-buffered w^T [j][i], swizzled
    __shared__ float denl[4][64];

    s16x8 Bh[4][2], Bl[4][2];     // resident z^T frags: rows j0..j0+63 (read before any write)
    #pragma unroll
    for (int nt=0;nt<4;nt++)
        #pragma unroll
        for (int ks=0;ks<2;ks++){
            size_t off = ((size_t)bg*HD + j0 + nt*16 + ln)*CD + ks*32 + quad*8;
            Bh[nt][ks] = ld8(zTh + off);
            Bl[nt][ks] = ld8(zTl + off);
        }
    float bj[4];
    #pragma unroll
    for (int nt=0;nt<4;nt++) bj[nt] = bias[(size_t)bg*HD + j0 + nt*16 + ln];

    f32x4 acc2[2][2] = {{z4(),z4()},{z4(),z4()}};
    float den[4] = {0.f,0.f,0.f,0.f};
    int buf = 0;

    for (int is=0; is<HD; is+=128, buf^=1){
        // ---- issue phase-A operand loads (q^T) ----
        s16x8 Ah[2][2], Al[2][2];
        #pragma unroll
        for (int ks=0;ks<2;ks++)
            #pragma unroll
            for (int mt=0;mt<2;mt++){
                size_t off = ((size_t)bg*HD + is + wave*32 + mt*16 + ln)*CD + ks*32 + quad*8;
                Ah[mt][ks] = ld8(qTh + off);
                Al[mt][ks] = ld8(qTl + off);
            }
        // ---- issue ALL phase-B operand loads (qN) ----
        s16x8 A2h[4][2], A2l[4][2];
        #pragma unroll
        for (int ks2=0;ks2<4;ks2++)
            #pragma unroll
            for (int mtN=0;mtN<2;mtN++){
                size_t off = ((size_t)bg*CD + cm + mtN*16 + ln)*HD + is + ks2*32 + quad*8;
                A2h[ks2][mtN] = ld8(qNh + off);
                A2l[ks2][mtN] = ld8(qNl + off);
            }
        // ---- r loads (vectorized) ----
        float ri[8];
        #pragma unroll
        for (int mt=0;mt<2;mt++){
            float4 rv = *(const float4*)&r[(size_t)bg*HD + is + wave*32 + mt*16 + quad*4];
            ri[mt*4+0] = __builtin_amdgcn_rcpf(rv.x);
            ri[mt*4+1] = __builtin_amdgcn_rcpf(rv.y);
            ri[mt*4+2] = __builtin_amdgcn_rcpf(rv.z);
            ri[mt*4+3] = __builtin_amdgcn_rcpf(rv.w);
        }
        // PIN: no load above may sink below this point.
        __builtin_amdgcn_sched_barrier(0);
        // ---- phase A MFMA ----
        f32x4 acc1[2][4];
        #pragma unroll
        for (int mt=0;mt<2;mt++)
            #pragma unroll
            for (int nt=0;nt<4;nt++) acc1[mt][nt] = z4();
        __builtin_amdgcn_s_setprio(1);
        #pragma unroll
        for (int ks=0;ks<2;ks++)
            #pragma unroll
            for (int mt=0;mt<2;mt++)
                #pragma unroll
                for (int nt=0;nt<4;nt++)
                    acc1[mt][nt] = mm3(Ah[mt][ks], Al[mt][ks], Bh[nt][ks], Bl[nt][ks], acc1[mt][nt]);
        __builtin_amdgcn_s_setprio(0);
        // ---- w compute + LDS write (buffer `buf`) ----
        #pragma unroll
        for (int mt=0;mt<2;mt++)
            #pragma unroll
            for (int nt=0;nt<4;nt++){
                u16 hh[4], ll[4];
                #pragma unroll
                for (int rx=0;rx<4;rx++){
                    float w = __expf(fmaf(a, acc1[mt][nt][rx], bj[nt])) * ri[mt*4+rx];
                    den[nt] += w;
                    split2(w, hh[rx], ll[rx]);
                }
                int row = nt*16 + ln;                        // j-local
                int c4  = wave*32 + mt*16 + quad*4;          // i-local
                int off = (row<<7) + ((((c4>>3) ^ (row&15))<<3) | (c4&7));
                *(ushort4*)&wlh[buf][off] = make_ushort4(hh[0],hh[1],hh[2],hh[3]);
                *(ushort4*)&wll[buf][off] = make_ushort4(ll[0],ll[1],ll[2],ll[3]);
            }
        __syncthreads();
        // ---- phase B: LDS reads + MFMA (global operands already in regs) ----
        __builtin_amdgcn_s_setprio(1);
        #pragma unroll
        for (int ks2=0;ks2<4;ks2++){
            s16x8 B2h[2], B2l[2];
            #pragma unroll
            for (int nt2=0;nt2<2;nt2++){
                int jl = jn + nt2*16 + ln;
                int ob = (jl<<7) + (((ks2*4+quad) ^ (jl&15))<<3);
                B2h[nt2] = ld8(&wlh[buf][ob]);
                B2l[nt2] = ld8(&wll[buf][ob]);
            }
            #pragma unroll
            for (int mtN=0;mtN<2;mtN++)
                #pragma unroll
                for (int nt2=0;nt2<2;nt2++)
                    acc2[mtN][nt2] = mm3(A2h[ks2][mtN], A2l[ks2][mtN], B2h[nt2], B2l[nt2], acc2[mtN][nt2]);
        }
        __builtin_amdgcn_s_setprio(0);
    }
    // denominator reduce: quads via shfl, waves via LDS
    #pragma unroll
    for (int nt=0;nt<4;nt++){
        float v = den[nt];
        v += __shfl_xor(v,16); v += __shfl_xor(v,32);
        if (quad == 0) denl[wave][nt*16 + ln] = v;
    }
    __syncthreads();
    #pragma unroll
    for (int nt2=0;nt2<2;nt2++){
        int jl = jn + nt2*16 + ln;
        float dinv = __builtin_amdgcn_rcpf(denl[0][jl]+denl[1][jl]+denl[2][jl]+denl[3][jl]);
        #pragma unroll
        for (int mtN=0;mtN<2;mtN++){
            u16 hh[4], ll[4];
            #pragma unroll
            for (int rx=0;rx<4;rx++){
                float v = acc2[mtN][nt2][rx] * dinv;
                split2(v, hh[rx], ll[rx]);
            }
            size_t off = ((size_t)bg*HD + j0 + jl)*CD + cm + mtN*16 + quad*4;
            *(ushort4*)(zTh + off) = make_ushort4(hh[0],hh[1],hh[2],hh[3]);
            *(ushort4*)(zTl + off) = make_ushort4(ll[0],ll[1],ll[2],ll[3]);
        }
    }
}

// final: out[c][i] = (sum_j e_ij mu_cj) / (sum_j e_ij). Same pinned-prefetch structure.
__global__ __launch_bounds__(256,2) void k_final(
    const u16* __restrict__ qTh, const u16* __restrict__ qTl,
    const u16* __restrict__ zTh, const u16* __restrict__ zTl,
    const u16* __restrict__ muh, const u16* __restrict__ mul_,
    const float* __restrict__ bias, const float* __restrict__ alpha,
    float* __restrict__ out)
{
    const int bg = blockIdx.y, i0 = blockIdx.x*64;
    const int tid = threadIdx.x, wave = tid>>6, lane = tid&63, ln = lane&15, quad = lane>>4;
    const int cm = (wave&1)*32, in_ = (wave>>1)*32;
    const float a = alpha[0];
    __shared__ u16 elh[2][64*128], ell[2][64*128];    // double-buffered e^T [i][j], swizzled
    __shared__ float rl2[4][64];

    s16x8 Bh[4][2], Bl[4][2];     // resident q^T frags: rows i0..i0+63 (n operand)
    #pragma unroll
    for (int nt=0;nt<4;nt++)
        #pragma unroll
        for (int ks=0;ks<2;ks++){
            size_t off = ((size_t)bg*HD + i0 + nt*16 + ln)*CD + ks*32 + quad*8;
            Bh[nt][ks] = ld8(qTh + off);
            Bl[nt][ks] = ld8(qTl + off);
        }
    f32x4 acc2[2][2] = {{z4(),z4()},{z4(),z4()}};
    float racc[4] = {0.f,0.f,0.f,0.f};
    int buf = 0;

    for (int js=0; js<HD; js+=128, buf^=1){
        // ---- issue phase-A operand loads (z^T) ----
        s16x8 Ah[2][2], Al[2][2];
        #pragma unroll
        for (int ks=0;ks<2;ks++)
            #pragma unroll
            for (int mt=0;mt<2;mt++){
                size_t off = ((size_t)bg*HD + js + wave*32 + mt*16 + ln)*CD + ks*32 + quad*8;
                Ah[mt][ks] = ld8(zTh + off);
                Al[mt][ks] = ld8(zTl + off);
            }
        // ---- issue ALL phase-B operand loads (mu) ----
        s16x8 A2h[4][2], A2l[4][2];
        #pragma unroll
        for (int ks2=0;ks2<4;ks2++)
            #pragma unroll
            for (int mtN=0;mtN<2;mtN++){
                size_t off = ((size_t)bg*CD + cm + mtN*16 + ln)*HD + js + ks2*32 + quad*8;
                A2h[ks2][mtN] = ld8(muh + off);
                A2l[ks2][mtN] = ld8(mul_ + off);
            }
        // ---- bias loads (vectorized) ----
        float bj8[8];
        #pragma unroll
        for (int mt=0;mt<2;mt++){
            float4 bv = *(const float4*)&bias[(size_t)bg*HD + js + wave*32 + mt*16 + quad*4];
            bj8[mt*4+0]=bv.x; bj8[mt*4+1]=bv.y; bj8[mt*4+2]=bv.z; bj8[mt*4+3]=bv.w;
        }
        // PIN: loads may not sink below.
        __builtin_amdgcn_sched_barrier(0);
        // ---- phase A MFMA: S'[j][i] (m = j, n = i) ----
        f32x4 acc1[2][4];
        #pragma unroll
        for (int mt=0;mt<2;mt++)
            #pragma unroll
            for (int nt=0;nt<4;nt++) acc1[mt][nt] = z4();
        __builtin_amdgcn_s_setprio(1);
        #pragma unroll
        for (int ks=0;ks<2;ks++)
            #pragma unroll
            for (int mt=0;mt<2;mt++)
                #pragma unroll
                for (int nt=0;nt<4;nt++)
                    acc1[mt][nt] = mm3(Ah[mt][ks], Al[mt][ks], Bh[nt][ks], Bl[nt][ks], acc1[mt][nt]);
        __builtin_amdgcn_s_setprio(0);
        // ---- e compute + LDS write (buffer `buf`) ----
        #pragma unroll
        for (int mt=0;mt<2;mt++)
            #pragma unroll
            for (int nt=0;nt<4;nt++){
                u16 hh[4], ll[4];
                #pragma unroll
                for (int rx=0;rx<4;rx++){
                    float e = __expf(fmaf(a, acc1[mt][nt][rx], bj8[mt*4+rx]));
                    racc[nt] += e;
                    split2(e, hh[rx], ll[rx]);
                }
                int row = nt*16 + ln;                        // i-local
                int c4  = wave*32 + mt*16 + quad*4;          // j-local
                int off = (row<<7) + ((((c4>>3) ^ (row&15))<<3) | (c4&7));
                *(ushort4*)&elh[buf][off] = make_ushort4(hh[0],hh[1],hh[2],hh[3]);
                *(ushort4*)&ell[buf][off] = make_ushort4(ll[0],ll[1],ll[2],ll[3]);
            }
        __syncthreads();
        // ---- phase B: acc2[c][i] += mu * e^T ----
        __builtin_amdgcn_s_setprio(1);
        #pragma unroll
        for (int ks2=0;ks2<4;ks2++){
            s16x8 B2h[2], B2l[2];
            #pragma unroll
            for (int nt2=0;nt2<2;nt2++){
                int il = in_ + nt2*16 + ln;
                int ob = (il<<7) + (((ks2*4+quad) ^ (il&15))<<3);
                B2h[nt2] = ld8(&elh[buf][ob]);
                B2l[nt2] = ld8(&ell[buf][ob]);
            }
            #pragma unroll
            for (int mtN=0;mtN<2;mtN++)
                #pragma unroll
                for (int nt2=0;nt2<2;nt2++)
                    acc2[mtN][nt2] = mm3(A2h[ks2][mtN], A2l[ks2][mtN], B2h[nt2], B2l[nt2], acc2[mtN][nt2]);
        }
        __builtin_amdgcn_s_setprio(0);
    }
    #pragma unroll
    for (int nt=0;nt<4;nt++){
        float v = racc[nt];
        v += __shfl_xor(v,16); v += __shfl_xor(v,32);
        if (quad == 0) rl2[wave][nt*16 + ln] = v;
    }
    __syncthreads();
    #pragma unroll
    for (int nt2=0;nt2<2;nt2++){
        int il = in_ + nt2*16 + ln;
        float rinv = __builtin_amdgcn_rcpf(rl2[0][il]+rl2[1][il]+rl2[2][il]+rl2[3][il]);
        #pragma unroll
        for (int mtN=0;mtN<2;mtN++)
            #pragma unroll
            for (int rx=0;rx<4;rx++)
                out[((size_t)bg*CD + cm + mtN*16 + quad*4 + rx)*HD + i0 + il]
                    = acc2[mtN][nt2][rx] * rinv;
    }
}

extern "C" void kernel_launch(void* const* d_in, const int* in_sizes, int n_in,
                              void* d_out, int out_size, void* d_ws, size_t ws_size,
                              hipStream_t stream)
{
    (void)in_sizes; (void)n_in; (void)out_size; (void)ws_size;
    const float* q     = (const float*)d_in[0];
    const float* zeta  = (const float*)d_in[1];
    const float* alpha = (const float*)d_in[2];
    const float* mu    = (const float*)d_in[3];
    const float* beta  = (const float*)d_in[4];
    float* out = (float*)d_out;

    const size_t SZ = (size_t)NB*HD*CD;   // elements per tensor
    u16* qTh = (u16*)d_ws;
    u16* qTl = qTh + 1*SZ;
    u16* zTh = qTh + 2*SZ;
    u16* zTl = qTh + 3*SZ;
    u16* qNh = qTh + 4*SZ;
    u16* qNl = qTh + 5*SZ;
    u16* muh = qTh + 6*SZ;
    u16* mul_= qTh + 7*SZ;
    float* bias = (float*)(qTh + 8*SZ);
    float* r    = bias + (size_t)NB*HD;

    dim3 blk(256,1,1);
    int n4 = (int)(SZ/4);
    k_convert  <<<dim3(n4/256), blk, 0, stream>>>(q,  qNh, qNl, n4);
    k_convert  <<<dim3(n4/256), blk, 0, stream>>>(mu, muh, mul_, n4);
    k_transpose<<<dim3(HD/128, NB), blk, 0, stream>>>(q,    qTh, qTl);
    k_transpose<<<dim3(HD/128, NB), blk, 0, stream>>>(zeta, zTh, zTl);
    k_bias     <<<dim3(HD/256, NB), blk, 0, stream>>>(mu, beta, bias);

    k_rowsum<<<dim3(HD/64, NB), blk, 0, stream>>>(qTh,qTl,zTh,zTl,bias,alpha,r);
    k_update<<<dim3(HD/64, NB), blk, 0, stream>>>(qTh,qTl,zTh,zTl,qNh,qNl,bias,alpha,r);
    k_rowsum<<<dim3(HD/64, NB), blk, 0, stream>>>(qTh,qTl,zTh,zTl,bias,alpha,r);
    k_update<<<dim3(HD/64, NB), blk, 0, stream>>>(qTh,qTl,zTh,zTl,qNh,qNl,bias,alpha,r);
    k_final <<<dim3(HD/64, NB), blk, 0, stream>>>(qTh,qTl,zTh,zTl,muh,mul_,bias,alpha,out);
}

// Round 10
// 499.273 us; speedup vs baseline: 2.1241x; 1.0043x over previous
//
#include <hip/hip_runtime.h>

#define NB 16    // N*G
#define CD 64    // C == Cv
#define HD 2048  // H

typedef unsigned short u16;
typedef __attribute__((ext_vector_type(8))) short s16x8;  // 8 bf16 (4 VGPRs)
typedef __attribute__((ext_vector_type(4))) float f32x4;  // MFMA C/D

__device__ __forceinline__ u16 f2bf(float x){
    unsigned u = __float_as_uint(x);
    u += 0x7FFFu + ((u >> 16) & 1u);   // RNE
    return (u16)(u >> 16);
}
__device__ __forceinline__ float bf2f(u16 h){ return __uint_as_float(((unsigned)h) << 16); }
__device__ __forceinline__ void split2(float x, u16& h, u16& l){
    h = f2bf(x); l = f2bf(x - bf2f(h));   // x - hi is exact in fp32
}
union Frag { uint4 q; s16x8 s; };
__device__ __forceinline__ s16x8 ld8(const u16* p){ Frag f; f.q = *(const uint4*)p; return f.s; }
__device__ __forceinline__ f32x4 mfma16(s16x8 a, s16x8 b, f32x4 c){
    return __builtin_amdgcn_mfma_f32_16x16x32_bf16(a, b, c, 0, 0, 0);
}
// fp32-emulating triple MFMA: hi*hi + hi*lo + lo*hi
__device__ __forceinline__ f32x4 mm3(s16x8 ah, s16x8 al, s16x8 bh, s16x8 bl, f32x4 c){
    c = mfma16(ah, bh, c);
    c = mfma16(ah, bl, c);
    c = mfma16(al, bh, c);
    return c;
}
__device__ __forceinline__ f32x4 z4(){ f32x4 v = {0.f,0.f,0.f,0.f}; return v; }

// XCD-aware swizzle: linear block lb -> (bg, tile) such that all blocks on one XCD
// (lb%8 == xcd, per round-robin dispatch) share bg in {2*xcd, 2*xcd+1}. Per-XCD L2
// then holds just 2 bgs' sweep operands (~4 MB) instead of slices of all 16 (32 MB).
__device__ __forceinline__ void xcd_map(int& bg, int& tile){
    int lb = blockIdx.y*32 + blockIdx.x;
    int xcd = lb & 7, t = lb >> 3;
    bg = 2*xcd + (t >> 5);
    tile = t & 31;
}

// ---------------- prep kernels (unchanged) ----------------

__global__ void k_convert(const float* __restrict__ src, u16* __restrict__ dh,
                          u16* __restrict__ dl, int n4)
{
    int idx = blockIdx.x*256 + threadIdx.x;
    if (idx >= n4) return;
    float4 v = ((const float4*)src)[idx];
    ushort4 h, l;
    split2(v.x, h.x, l.x); split2(v.y, h.y, l.y);
    split2(v.z, h.z, l.z); split2(v.w, h.w, l.w);
    ((ushort4*)dh)[idx] = h;
    ((ushort4*)dl)[idx] = l;
}

__global__ void k_transpose(const float* __restrict__ src, u16* __restrict__ dh,
                            u16* __restrict__ dl)
{
    int bg = blockIdx.y, h0 = blockIdx.x*128, tid = threadIdx.x;
    __shared__ float ft[CD][132];
    #pragma unroll
    for (int k=0;k<8;k++){
        int flat = tid + 256*k;
        int c = flat >> 5, p = (flat & 31)*4;
        *(float4*)&ft[c][p] = *(const float4*)(src + ((size_t)bg*CD + c)*HD + h0 + p);
    }
    __syncthreads();
    int hl = tid >> 1, c0 = (tid & 1)*32;
    union { u16 u[32]; uint4 q[4]; } oh, ol;
    #pragma unroll
    for (int m=0;m<32;m++){
        float x = ft[c0+m][hl];
        u16 hh; split2(x, hh, ol.u[m]); oh.u[m] = hh;
    }
    size_t base = ((size_t)bg*HD + h0 + hl)*CD + c0;
    #pragma unroll
    for (int t=0;t<4;t++){
        *((uint4*)(dh + base) + t) = oh.q[t];
        *((uint4*)(dl + base) + t) = ol.q[t];
    }
}

__global__ void k_bias(const float* __restrict__ mu, const float* __restrict__ beta,
                       float* __restrict__ bias)
{
    int bg = blockIdx.y;
    int j  = blockIdx.x*256 + threadIdx.x;
    const float* m = mu + (size_t)bg*CD*HD + j;
    float s = 0.f;
    #pragma unroll
    for (int c=0;c<CD;c++){ float v = m[(size_t)c*HD]; s = fmaf(v, v, s); }
    bias[(size_t)bg*HD + j] = 0.5f * beta[0] * s;
}

// ---------------- main MFMA kernels ----------------

// r[i] = sum_j exp(a*S+bias_j). Block: 64 i-rows, waves split j; B tile double-buffered.
__global__ __launch_bounds__(256,2) void k_rowsum(
    const u16* __restrict__ qTh, const u16* __restrict__ qTl,
    const u16* __restrict__ zTh, const u16* __restrict__ zTl,
    const float* __restrict__ bias, const float* __restrict__ alpha,
    float* __restrict__ r)
{
    int bg, itile; xcd_map(bg, itile);
    const int i0 = itile*64;
    const int tid = threadIdx.x, wave = tid>>6, lane = tid&63, ln = lane&15, quad = lane>>4;
    const int jw = wave*32;
    const float a = alpha[0];
    __shared__ float rpart[4][64];

    s16x8 Ah[4][2], Al[4][2];     // resident q^T frags: rows i0..i0+63
    #pragma unroll
    for (int mt=0;mt<4;mt++)
        #pragma unroll
        for (int ks=0;ks<2;ks++){
            size_t off = ((size_t)bg*HD + i0 + mt*16 + ln)*CD + ks*32 + quad*8;
            Ah[mt][ks] = ld8(qTh + off);
            Al[mt][ks] = ld8(qTl + off);
        }
    float racc[16];
    #pragma unroll
    for (int k=0;k<16;k++) racc[k] = 0.f;
    const float* bb = bias + (size_t)bg*HD;

    s16x8 B0h[2][2], B0l[2][2], B1h[2][2], B1l[2][2];
    float bj0[2], bj1[2];

    // prologue: tile 0
    #pragma unroll
    for (int nt=0;nt<2;nt++){
        #pragma unroll
        for (int ks=0;ks<2;ks++){
            size_t off = ((size_t)bg*HD + jw + nt*16 + ln)*CD + ks*32 + quad*8;
            B0h[nt][ks] = ld8(zTh + off);
            B0l[nt][ks] = ld8(zTl + off);
        }
        bj0[nt] = bb[jw + nt*16 + ln];
    }

    for (int j0=0;j0<HD;j0+=256){
        // issue loads for tile j0+128 into B1, pinned above the B0 compute
        #pragma unroll
        for (int nt=0;nt<2;nt++){
            #pragma unroll
            for (int ks=0;ks<2;ks++){
                size_t off = ((size_t)bg*HD + j0+128 + jw + nt*16 + ln)*CD + ks*32 + quad*8;
                B1h[nt][ks] = ld8(zTh + off);
                B1l[nt][ks] = ld8(zTl + off);
            }
            bj1[nt] = bb[j0+128 + jw + nt*16 + ln];
        }
        __builtin_amdgcn_sched_barrier(0);
        // compute tile j0 with B0
        {
            f32x4 acc[4][2];
            #pragma unroll
            for (int mt=0;mt<4;mt++){ acc[mt][0]=z4(); acc[mt][1]=z4(); }
            __builtin_amdgcn_s_setprio(1);
            #pragma unroll
            for (int ks=0;ks<2;ks++)
                #pragma unroll
                for (int mt=0;mt<4;mt++)
                    #pragma unroll
                    for (int nt=0;nt<2;nt++)
                        acc[mt][nt] = mm3(Ah[mt][ks], Al[mt][ks], B0h[nt][ks], B0l[nt][ks], acc[mt][nt]);
            __builtin_amdgcn_s_setprio(0);
            #pragma unroll
            for (int mt=0;mt<4;mt++)
                #pragma unroll
                for (int nt=0;nt<2;nt++)
                    #pragma unroll
                    for (int rx=0;rx<4;rx++)
                        racc[mt*4+rx] += __expf(fmaf(a, acc[mt][nt][rx], bj0[nt]));
        }
        // issue loads for tile (j0+256)&(HD-1) into B0, pinned above the B1 compute
        {
            int jn2 = (j0+256) & (HD-1);
            #pragma unroll
            for (int nt=0;nt<2;nt++){
                #pragma unroll
                for (int ks=0;ks<2;ks++){
                    size_t off = ((size_t)bg*HD + jn2 + jw + nt*16 + ln)*CD + ks*32 + quad*8;
                    B0h[nt][ks] = ld8(zTh + off);
                    B0l[nt][ks] = ld8(zTl + off);
                }
                bj0[nt] = bb[jn2 + jw + nt*16 + ln];
            }
        }
        __builtin_amdgcn_sched_barrier(0);
        // compute tile j0+128 with B1
        {
            f32x4 acc[4][2];
            #pragma unroll
            for (int mt=0;mt<4;mt++){ acc[mt][0]=z4(); acc[mt][1]=z4(); }
            __builtin_amdgcn_s_setprio(1);
            #pragma unroll
            for (int ks=0;ks<2;ks++)
                #pragma unroll
                for (int mt=0;mt<4;mt++)
                    #pragma unroll
                    for (int nt=0;nt<2;nt++)
                        acc[mt][nt] = mm3(Ah[mt][ks], Al[mt][ks], B1h[nt][ks], B1l[nt][ks], acc[mt][nt]);
            __builtin_amdgcn_s_setprio(0);
            #pragma unroll
            for (int mt=0;mt<4;mt++)
                #pragma unroll
                for (int nt=0;nt<2;nt++)
                    #pragma unroll
                    for (int rx=0;rx<4;rx++)
                        racc[mt*4+rx] += __expf(fmaf(a, acc[mt][nt][rx], bj1[nt]));
        }
    }
    #pragma unroll
    for (int k=0;k<16;k++){
        float v = racc[k];
        v += __shfl_xor(v,1); v += __shfl_xor(v,2);
        v += __shfl_xor(v,4); v += __shfl_xor(v,8);
        racc[k] = v;
    }
    if (ln == 0){
        #pragma unroll
        for (int mt=0;mt<4;mt++)
            #pragma unroll
            for (int rx=0;rx<4;rx++)
                rpart[wave][mt*16 + quad*4 + rx] = racc[mt*4+rx];
    }
    __syncthreads();
    if (tid < 64)
        r[(size_t)bg*HD + i0 + tid] = rpart[0][tid]+rpart[1][tid]+rpart[2][tid]+rpart[3][tid];
}

// zeta update. Block: 64 j-cols, sweeps i (128/step). LDS w-tile double-buffered.
__global__ __launch_bounds__(256,2) void k_update(
    const u16* __restrict__ qTh, const u16* __restrict__ qTl,
    u16* zTh, u16* zTl,                               // read then overwritten (own rows only)
    const u16* __restrict__ qNh, const u16* __restrict__ qNl,
    const float* __restrict__ bias, const float* __restrict__ alpha,
    const float* __restrict__ r)
{
    int bg, jtile; xcd_map(bg, jtile);
    const int j0 = jtile*64;
    const int tid = threadIdx.x, wave = tid>>6, lane = tid&63, ln = lane&15, quad = lane>>4;
    const int cm = (wave&1)*32, jn = (wave>>1)*32;
    const float a = alpha[0];
    __shared__ u16 wlh[2][64*128], wll[2][64*128];    // double-buffered w^T [j][i], swizzled
    __shared__ float denl[4][64];

    s16x8 Bh[4][2], Bl[4][2];     // resident z^T frags: rows j0..j0+63 (read before any write)
    #pragma unroll
    for (int nt=0;nt<4;nt++)
        #pragma unroll
        for (int ks=0;ks<2;ks++){
            size_t off = ((size_t)bg*HD + j0 + nt*16 + ln)*CD + ks*32 + quad*8;
            Bh[nt][ks] = ld8(zTh + off);
            Bl[nt][ks] = ld8(zTl + off);
        }
    float bj[4];
    #pragma unroll
    for (int nt=0;nt<4;nt++) bj[nt] = bias[(size_t)bg*HD + j0 + nt*16 + ln];

    f32x4 acc2[2][2] = {{z4(),z4()},{z4(),z4()}};
    float den[4] = {0.f,0.f,0.f,0.f};
    int buf = 0;

    for (int is=0; is<HD; is+=128, buf^=1){
        // ---- issue phase-A operand loads (q^T) ----
        s16x8 Ah[2][2], Al[2][2];
        #pragma unroll
        for (int ks=0;ks<2;ks++)
            #pragma unroll
            for (int mt=0;mt<2;mt++){
                size_t off = ((size_t)bg*HD + is + wave*32 + mt*16 + ln)*CD + ks*32 + quad*8;
                Ah[mt][ks] = ld8(qTh + off);
                Al[mt][ks] = ld8(qTl + off);
            }
        // ---- issue ALL phase-B operand loads (qN) ----
        s16x8 A2h[4][2], A2l[4][2];
        #pragma unroll
        for (int ks2=0;ks2<4;ks2++)
            #pragma unroll
            for (int mtN=0;mtN<2;mtN++){
                size_t off = ((size_t)bg*CD + cm + mtN*16 + ln)*HD + is + ks2*32 + quad*8;
                A2h[ks2][mtN] = ld8(qNh + off);
                A2l[ks2][mtN] = ld8(qNl + off);
            }
        // ---- r loads (vectorized) ----
        float ri[8];
        #pragma unroll
        for (int mt=0;mt<2;mt++){
            float4 rv = *(const float4*)&r[(size_t)bg*HD + is + wave*32 + mt*16 + quad*4];
            ri[mt*4+0] = __builtin_amdgcn_rcpf(rv.x);
            ri[mt*4+1] = __builtin_amdgcn_rcpf(rv.y);
            ri[mt*4+2] = __builtin_amdgcn_rcpf(rv.z);
            ri[mt*4+3] = __builtin_amdgcn_rcpf(rv.w);
        }
        // PIN: no load above may sink below this point.
        __builtin_amdgcn_sched_barrier(0);
        // ---- phase A MFMA ----
        f32x4 acc1[2][4];
        #pragma unroll
        for (int mt=0;mt<2;mt++)
            #pragma unroll
            for (int nt=0;nt<4;nt++) acc1[mt][nt] = z4();
        __builtin_amdgcn_s_setprio(1);
        #pragma unroll
        for (int ks=0;ks<2;ks++)
            #pragma unroll
            for (int mt=0;mt<2;mt++)
                #pragma unroll
                for (int nt=0;nt<4;nt++)
                    acc1[mt][nt] = mm3(Ah[mt][ks], Al[mt][ks], Bh[nt][ks], Bl[nt][ks], acc1[mt][nt]);
        __builtin_amdgcn_s_setprio(0);
        // ---- w compute + LDS write (buffer `buf`) ----
        #pragma unroll
        for (int mt=0;mt<2;mt++)
            #pragma unroll
            for (int nt=0;nt<4;nt++){
                u16 hh[4], ll[4];
                #pragma unroll
                for (int rx=0;rx<4;rx++){
                    float w = __expf(fmaf(a, acc1[mt][nt][rx], bj[nt])) * ri[mt*4+rx];
                    den[nt] += w;
                    split2(w, hh[rx], ll[rx]);
                }
                int row = nt*16 + ln;                        // j-local
                int c4  = wave*32 + mt*16 + quad*4;          // i-local
                int off = (row<<7) + ((((c4>>3) ^ (row&15))<<3) | (c4&7));
                *(ushort4*)&wlh[buf][off] = make_ushort4(hh[0],hh[1],hh[2],hh[3]);
                *(ushort4*)&wll[buf][off] = make_ushort4(ll[0],ll[1],ll[2],ll[3]);
            }
        __syncthreads();
        // ---- phase B: LDS reads + MFMA (global operands already in regs) ----
        __builtin_amdgcn_s_setprio(1);
        #pragma unroll
        for (int ks2=0;ks2<4;ks2++){
            s16x8 B2h[2], B2l[2];
            #pragma unroll
            for (int nt2=0;nt2<2;nt2++){
                int jl = jn + nt2*16 + ln;
                int ob = (jl<<7) + (((ks2*4+quad) ^ (jl&15))<<3);
                B2h[nt2] = ld8(&wlh[buf][ob]);
                B2l[nt2] = ld8(&wll[buf][ob]);
            }
            #pragma unroll
            for (int mtN=0;mtN<2;mtN++)
                #pragma unroll
                for (int nt2=0;nt2<2;nt2++)
                    acc2[mtN][nt2] = mm3(A2h[ks2][mtN], A2l[ks2][mtN], B2h[nt2], B2l[nt2], acc2[mtN][nt2]);
        }
        __builtin_amdgcn_s_setprio(0);
    }
    // denominator reduce: quads via shfl, waves via LDS
    #pragma unroll
    for (int nt=0;nt<4;nt++){
        float v = den[nt];
        v += __shfl_xor(v,16); v += __shfl_xor(v,32);
        if (quad == 0) denl[wave][nt*16 + ln] = v;
    }
    __syncthreads();
    #pragma unroll
    for (int nt2=0;nt2<2;nt2++){
        int jl = jn + nt2*16 + ln;
        float dinv = __builtin_amdgcn_rcpf(denl[0][jl]+denl[1][jl]+denl[2][jl]+denl[3][jl]);
        #pragma unroll
        for (int mtN=0;mtN<2;mtN++){
            u16 hh[4], ll[4];
            #pragma unroll
            for (int rx=0;rx<4;rx++){
                float v = acc2[mtN][nt2][rx] * dinv;
                split2(v, hh[rx], ll[rx]);
            }
            size_t off = ((size_t)bg*HD + j0 + jl)*CD + cm + mtN*16 + quad*4;
            *(ushort4*)(zTh + off) = make_ushort4(hh[0],hh[1],hh[2],hh[3]);
            *(ushort4*)(zTl + off) = make_ushort4(ll[0],ll[1],ll[2],ll[3]);
        }
    }
}

// final: out[c][i] = (sum_j e_ij mu_cj) / (sum_j e_ij). Same structure.
__global__ __launch_bounds__(256,2) void k_final(
    const u16* __restrict__ qTh, const u16* __restrict__ qTl,
    const u16* __restrict__ zTh, const u16* __restrict__ zTl,
    const u16* __restrict__ muh, const u16* __restrict__ mul_,
    const float* __restrict__ bias, const float* __restrict__ alpha,
    float* __restrict__ out)
{
    int bg, itile; xcd_map(bg, itile);
    const int i0 = itile*64;
    const int tid = threadIdx.x, wave = tid>>6, lane = tid&63, ln = lane&15, quad = lane>>4;
    const int cm = (wave&1)*32, in_ = (wave>>1)*32;
    const float a = alpha[0];
    __shared__ u16 elh[2][64*128], ell[2][64*128];    // double-buffered e^T [i][j], swizzled
    __shared__ float rl2[4][64];

    s16x8 Bh[4][2], Bl[4][2];     // resident q^T frags: rows i0..i0+63 (n operand)
    #pragma unroll
    for (int nt=0;nt<4;nt++)
        #pragma unroll
        for (int ks=0;ks<2;ks++){
            size_t off = ((size_t)bg*HD + i0 + nt*16 + ln)*CD + ks*32 + quad*8;
            Bh[nt][ks] = ld8(qTh + off);
            Bl[nt][ks] = ld8(qTl + off);
        }
    f32x4 acc2[2][2] = {{z4(),z4()},{z4(),z4()}};
    float racc[4] = {0.f,0.f,0.f,0.f};
    int buf = 0;

    for (int js=0; js<HD; js+=128, buf^=1){
        // ---- issue phase-A operand loads (z^T) ----
        s16x8 Ah[2][2], Al[2][2];
        #pragma unroll
        for (int ks=0;ks<2;ks++)
            #pragma unroll
            for (int mt=0;mt<2;mt++){
                size_t off = ((size_t)bg*HD + js + wave*32 + mt*16 + ln)*CD + ks*32 + quad*8;
                Ah[mt][ks] = ld8(zTh + off);
                Al[mt][ks] = ld8(zTl + off);
            }
        // ---- issue ALL phase-B operand loads (mu) ----
        s16x8 A2h[4][2], A2l[4][2];
        #pragma unroll
        for (int ks2=0;ks2<4;ks2++)
            #pragma unroll
            for (int mtN=0;mtN<2;mtN++){
                size_t off = ((size_t)bg*CD + cm + mtN*16 + ln)*HD + js + ks2*32 + quad*8;
                A2h[ks2][mtN] = ld8(muh + off);
                A2l[ks2][mtN] = ld8(mul_ + off);
            }
        // ---- bias loads (vectorized) ----
        float bj8[8];
        #pragma unroll
        for (int mt=0;mt<2;mt++){
            float4 bv = *(const float4*)&bias[(size_t)bg*HD + js + wave*32 + mt*16 + quad*4];
            bj8[mt*4+0]=bv.x; bj8[mt*4+1]=bv.y; bj8[mt*4+2]=bv.z; bj8[mt*4+3]=bv.w;
        }
        // PIN: loads may not sink below.
        __builtin_amdgcn_sched_barrier(0);
        // ---- phase A MFMA: S'[j][i] (m = j, n = i) ----
        f32x4 acc1[2][4];
        #pragma unroll
        for (int mt=0;mt<2;mt++)
            #pragma unroll
            for (int nt=0;nt<4;nt++) acc1[mt][nt] = z4();
        __builtin_amdgcn_s_setprio(1);
        #pragma unroll
        for (int ks=0;ks<2;ks++)
            #pragma unroll
            for (int mt=0;mt<2;mt++)
                #pragma unroll
                for (int nt=0;nt<4;nt++)
                    acc1[mt][nt] = mm3(Ah[mt][ks], Al[mt][ks], Bh[nt][ks], Bl[nt][ks], acc1[mt][nt]);
        __builtin_amdgcn_s_setprio(0);
        // ---- e compute + LDS write (buffer `buf`) ----
        #pragma unroll
        for (int mt=0;mt<2;mt++)
            #pragma unroll
            for (int nt=0;nt<4;nt++){
                u16 hh[4], ll[4];
                #pragma unroll
                for (int rx=0;rx<4;rx++){
                    float e = __expf(fmaf(a, acc1[mt][nt][rx], bj8[mt*4+rx]));
                    racc[nt] += e;
                    split2(e, hh[rx], ll[rx]);
                }
                int row = nt*16 + ln;                        // i-local
                int c4  = wave*32 + mt*16 + quad*4;          // j-local
                int off = (row<<7) + ((((c4>>3) ^ (row&15))<<3) | (c4&7));
                *(ushort4*)&elh[buf][off] = make_ushort4(hh[0],hh[1],hh[2],hh[3]);
                *(ushort4*)&ell[buf][off] = make_ushort4(ll[0],ll[1],ll[2],ll[3]);
            }
        __syncthreads();
        // ---- phase B: acc2[c][i] += mu * e^T ----
        __builtin_amdgcn_s_setprio(1);
        #pragma unroll
        for (int ks2=0;ks2<4;ks2++){
            s16x8 B2h[2], B2l[2];
            #pragma unroll
            for (int nt2=0;nt2<2;nt2++){
                int il = in_ + nt2*16 + ln;
                int ob = (il<<7) + (((ks2*4+quad) ^ (il&15))<<3);
                B2h[nt2] = ld8(&elh[buf][ob]);
                B2l[nt2] = ld8(&ell[buf][ob]);
            }
            #pragma unroll
            for (int mtN=0;mtN<2;mtN++)
                #pragma unroll
                for (int nt2=0;nt2<2;nt2++)
                    acc2[mtN][nt2] = mm3(A2h[ks2][mtN], A2l[ks2][mtN], B2h[nt2], B2l[nt2], acc2[mtN][nt2]);
        }
        __builtin_amdgcn_s_setprio(0);
    }
    #pragma unroll
    for (int nt=0;nt<4;nt++){
        float v = racc[nt];
        v += __shfl_xor(v,16); v += __shfl_xor(v,32);
        if (quad == 0) rl2[wave][nt*16 + ln] = v;
    }
    __syncthreads();
    #pragma unroll
    for (int nt2=0;nt2<2;nt2++){
        int il = in_ + nt2*16 + ln;
        float rinv = __builtin_amdgcn_rcpf(rl2[0][il]+rl2[1][il]+rl2[2][il]+rl2[3][il]);
        #pragma unroll
        for (int mtN=0;mtN<2;mtN++)
            #pragma unroll
            for (int rx=0;rx<4;rx++)
                out[((size_t)bg*CD + cm + mtN*16 + quad*4 + rx)*HD + i0 + il]
                    = acc2[mtN][nt2][rx] * rinv;
    }
}

extern "C" void kernel_launch(void* const* d_in, const int* in_sizes, int n_in,
                              void* d_out, int out_size, void* d_ws, size_t ws_size,
                              hipStream_t stream)
{
    (void)in_sizes; (void)n_in; (void)out_size; (void)ws_size;
    const float* q     = (const float*)d_in[0];
    const float* zeta  = (const float*)d_in[1];
    const float* alpha = (const float*)d_in[2];
    const float* mu    = (const float*)d_in[3];
    const float* beta  = (const float*)d_in[4];
    float* out = (float*)d_out;

    const size_t SZ = (size_t)NB*HD*CD;   // elements per tensor
    u16* qTh = (u16*)d_ws;
    u16* qTl = qTh + 1*SZ;
    u16* zTh = qTh + 2*SZ;
    u16* zTl = qTh + 3*SZ;
    u16* qNh = qTh + 4*SZ;
    u16* qNl = qTh + 5*SZ;
    u16* muh = qTh + 6*SZ;
    u16* mul_= qTh + 7*SZ;
    float* bias = (float*)(qTh + 8*SZ);
    float* r    = bias + (size_t)NB*HD;

    dim3 blk(256,1,1);
    int n4 = (int)(SZ/4);
    k_convert  <<<dim3(n4/256), blk, 0, stream>>>(q,  qNh, qNl, n4);
    k_convert  <<<dim3(n4/256), blk, 0, stream>>>(mu, muh, mul_, n4);
    k_transpose<<<dim3(HD/128, NB), blk, 0, stream>>>(q,    qTh, qTl);
    k_transpose<<<dim3(HD/128, NB), blk, 0, stream>>>(zeta, zTh, zTl);
    k_bias     <<<dim3(HD/256, NB), blk, 0, stream>>>(mu, beta, bias);

    k_rowsum<<<dim3(HD/64, NB), blk, 0, stream>>>(qTh,qTl,zTh,zTl,bias,alpha,r);
    k_update<<<dim3(HD/64, NB), blk, 0, stream>>>(qTh,qTl,zTh,zTl,qNh,qNl,bias,alpha,r);
    k_rowsum<<<dim3(HD/64, NB), blk, 0, stream>>>(qTh,qTl,zTh,zTl,bias,alpha,r);
    k_update<<<dim3(HD/64, NB), blk, 0, stream>>>(qTh,qTl,zTh,zTl,qNh,qNl,bias,alpha,r);
    k_final <<<dim3(HD/64, NB), blk, 0, stream>>>(qTh,qTl,zTh,zTl,muh,mul_,bias,alpha,out);
}